// Round 3
// baseline (302.495 us; speedup 1.0000x reference)
//
#include <hip/hip_runtime.h>
#include <cstdint>

typedef __bf16 bf16;
typedef __attribute__((ext_vector_type(8))) __bf16 bf16x8;
typedef __attribute__((ext_vector_type(4))) __bf16 bf16x4;
typedef __attribute__((ext_vector_type(4))) float f32x4;

#define T_TOK 8192
#define IN_F  2048
#define OUT_F 2048
#define GATE_N 128    // E * GK = 8 * 16
#define Z_COLS 256    // svh rows (8 experts x 32)
#define A2C 320       // 256 zw + 8 w + 1 one + 55 zero pad
#define K2_TOT 2368   // 2048 + 320
#define GATE_KS 4     // split-K slices for fp32 gate GEMM (fallback path)

// ---- workspace layout (bytes) ----
#define WS_XB  0                      // bf16 xb   8192*2048*2 = 33554432
#define WS_GG  33554432               // fp32 Gg   8192*128*4  =  4194304
#define WS_A2  37748736               // bf16 A2   8192*320*2  =  5242880
#define WS_B2  42991616               // bf16 B2   2048*320*2  =  1310720
#define WS_WZ  44302336               // bf16 Wz   256*2048*2  =  1048576
#define WS_WB  45350912               // bf16 Wb   2048*2048*2 =  8388608
#define WS_XL  53739520               // bf16 xl   8192*2048*2 = 33554432 (hi/lo gate path)
#define WS_GH  87293952               // bf16 gh   128*2048*2  =   524288
#define WS_GL  87818240               // bf16 gl   128*2048*2  =   524288
#define WS_TOTAL_MFMA_GATE 88342528ULL

// async 16B global->LDS; LDS dest is wave-uniform base, HW scatters lane i at
// base + i*16 (m104/m108). R1-proven incantation.
__device__ __forceinline__ void async_cp16(const bf16* g, bf16* l) {
  __builtin_amdgcn_global_load_lds(
      (const __attribute__((address_space(1))) void*)reinterpret_cast<uintptr_t>(g),
      (__attribute__((address_space(3))) void*)(uint32_t)reinterpret_cast<uintptr_t>(l),
      16, 0, 0);
}

// Convert fp32 inputs to bf16 workspace tensors. When xl/gh/gl are non-null
// (MFMA-gate path), additionally emit the bf16 lo-residuals for the
// split-precision gate GEMM: x = xh + xl, gw = gh + gl, each term bf16.
__global__ void prep_kernel(const float* __restrict__ x, const float* __restrict__ W,
                            const float* __restrict__ svh,
                            const float* __restrict__ u, const float* __restrict__ eb,
                            const float* __restrict__ b, const float* __restrict__ gw,
                            bf16* __restrict__ xb, bf16* __restrict__ Wb,
                            bf16* __restrict__ Wz, bf16* __restrict__ B2,
                            bf16* __restrict__ xl, bf16* __restrict__ gh,
                            bf16* __restrict__ gl) {
  const int idx = blockIdx.x * 256 + threadIdx.x;
  const int nt  = gridDim.x * 256;

  const int nx4 = (T_TOK * IN_F) / 4;
  for (int i = idx; i < nx4; i += nt) {
    const float4 v = ((const float4*)x)[i];
    bf16x4 o = {(bf16)v.x, (bf16)v.y, (bf16)v.z, (bf16)v.w};
    *(bf16x4*)&xb[(size_t)i * 4] = o;
    if (xl) {
      bf16x4 l = {(bf16)(v.x - (float)o.x), (bf16)(v.y - (float)o.y),
                  (bf16)(v.z - (float)o.z), (bf16)(v.w - (float)o.w)};
      *(bf16x4*)&xl[(size_t)i * 4] = l;
    }
  }
  if (gh) {
    const int ng4 = (GATE_N * IN_F) / 4;
    for (int i = idx; i < ng4; i += nt) {
      const float4 v = ((const float4*)gw)[i];
      bf16x4 h = {(bf16)v.x, (bf16)v.y, (bf16)v.z, (bf16)v.w};
      *(bf16x4*)&gh[(size_t)i * 4] = h;
      bf16x4 l = {(bf16)(v.x - (float)h.x), (bf16)(v.y - (float)h.y),
                  (bf16)(v.z - (float)h.z), (bf16)(v.w - (float)h.w)};
      *(bf16x4*)&gl[(size_t)i * 4] = l;
    }
  }
  const int nw4 = (OUT_F * IN_F) / 4;
  for (int i = idx; i < nw4; i += nt) {
    const float4 v = ((const float4*)W)[i];
    bf16x4 o = {(bf16)v.x, (bf16)v.y, (bf16)v.z, (bf16)v.w};
    *(bf16x4*)&Wb[(size_t)i * 4] = o;
  }
  const int nz4 = (Z_COLS * IN_F) / 4;   // svh flat [256][2048]
  for (int i = idx; i < nz4; i += nt) {
    const float4 v = ((const float4*)svh)[i];
    bf16x4 o = {(bf16)v.x, (bf16)v.y, (bf16)v.z, (bf16)v.w};
    *(bf16x4*)&Wz[(size_t)i * 4] = o;
  }
  // B2[o][j]: j<256 -> u[e=j>>5][o][k=j&31]; 256..263 -> eb[j-256][o]; 264 -> b[o]; else 0
  for (int i = idx; i < OUT_F * A2C; i += nt) {
    const int o = i / A2C, j = i - o * A2C;
    float v;
    if (j < 256) {
      const int e = j >> 5, k = j & 31;
      v = u[((size_t)(e * OUT_F + o)) * 32 + k];
    } else if (j < 264) {
      v = eb[(size_t)(j - 256) * OUT_F + o];
    } else if (j == 264) {
      v = b[o];
    } else {
      v = 0.f;
    }
    B2[i] = (bf16)v;
  }
}

// fp32 VALU gate GEMM fallback (only used if ws_size can't fit the hi/lo
// buffers). Split-K x4 (blockIdx.z), atomicAdd epilogue into zeroed Gg.
__global__ __launch_bounds__(256) void vgemm_gate(
    const float* __restrict__ x, const float* __restrict__ gw,
    float* __restrict__ Gg) {
  __shared__ float As[64][37];
  __shared__ float Bs[64][37];
  const int tid = threadIdx.x;
  const int tx = tid & 15, ty = tid >> 4;
  const int gm0 = blockIdx.y * 64, gn0 = blockIdx.x * 64;
  const int kbeg = blockIdx.z * (IN_F / GATE_KS);
  const int kend = kbeg + (IN_F / GATE_KS);

  float acc[4][4] = {};
  for (int k0 = kbeg; k0 < kend; k0 += 32) {
    __syncthreads();
#pragma unroll
    for (int it = 0; it < 2; ++it) {
      const int idx = it * 256 + tid;
      const int r = idx >> 3, c4 = (idx & 7) * 4;
      const float4 av = *(const float4*)(x + (size_t)(gm0 + r) * IN_F + k0 + c4);
      As[r][c4 + 0] = av.x; As[r][c4 + 1] = av.y;
      As[r][c4 + 2] = av.z; As[r][c4 + 3] = av.w;
      const float4 bv = *(const float4*)(gw + (size_t)(gn0 + r) * IN_F + k0 + c4);
      Bs[r][c4 + 0] = bv.x; Bs[r][c4 + 1] = bv.y;
      Bs[r][c4 + 2] = bv.z; Bs[r][c4 + 3] = bv.w;
    }
    __syncthreads();
#pragma unroll 4
    for (int k = 0; k < 32; ++k) {
      float a[4], bb[4];
#pragma unroll
      for (int i = 0; i < 4; ++i) a[i] = As[4 * ty + i][k];
#pragma unroll
      for (int j = 0; j < 4; ++j) bb[j] = Bs[4 * tx + j][k];
#pragma unroll
      for (int i = 0; i < 4; ++i)
#pragma unroll
        for (int j = 0; j < 4; ++j) acc[i][j] += a[i] * bb[j];
    }
  }
#pragma unroll
  for (int i = 0; i < 4; ++i)
#pragma unroll
    for (int j = 0; j < 4; ++j)
      atomicAdd(&Gg[(size_t)(gm0 + 4 * ty + i) * 128 + (gn0 + 4 * tx + j)],
                acc[i][j]);
}

// Fused gate+z GEMM, 768 blocks, direct stores (no atomics, no memsets).
// Blocks 0..255: gate logits Gg[8192][128] = xh@gh^T + xh@gl^T + xl@gh^T
//   (3 K-segments, K=6144 total, fp32 store — one block owns its tile).
// Blocks 256..767: z = xb @ Wz^T, K=2048, bf16 store into A2 cols 0..255
//   (ldc=A2C=320; router later scales in place and fills cols 256..319).
// Round-robin XCD dispatch spreads the 3x-heavier gate blocks evenly.
// Same m97-rung inner structure as gemm_bt (async_cp16 + XOR swizzle).
__global__ __launch_bounds__(256, 2) void gatez_gemm(
    const bf16* __restrict__ xb, const bf16* __restrict__ xl,
    const bf16* __restrict__ gh, const bf16* __restrict__ gl,
    const bf16* __restrict__ Wz,
    float* __restrict__ Gg, bf16* __restrict__ A2) {
  constexpr int BK = 64;
  __shared__ __align__(16) bf16 As[64 * BK];
  __shared__ __align__(16) bf16 Bs[64 * BK];

  const int tid  = threadIdx.x;
  const int lane = tid & 63;
  const int ml   = lane & 15;
  const int q    = lane >> 4;
  const int wave = tid >> 6;

  const int blk = blockIdx.x;
  const bool isgate = blk < 256;
  int gm0, gn0, nkt;
  if (isgate) { gm0 = (blk >> 1) * 64; gn0 = (blk & 1) * 64; nkt = 96; }
  else { const int t = blk - 256; gm0 = (t >> 2) * 64; gn0 = (t & 3) * 64; nkt = 32; }

  const int wr = wave >> 1, wc = wave & 1;
  const int wm0 = wr * 32, wn0 = wc * 32;

  f32x4 acc[2][2];
  const f32x4 zero = {0.f, 0.f, 0.f, 0.f};
#pragma unroll
  for (int i = 0; i < 2; ++i)
#pragma unroll
    for (int j = 0; j < 2; ++j) acc[i][j] = zero;

  for (int kt = 0; kt < nkt; ++kt) {
    const int k0 = kt * BK;
    const bf16* Ap; const bf16* Bp; int ka;
    if (!isgate)        { Ap = xb; Bp = Wz; ka = k0; }
    else if (k0 < 2048) { Ap = xb; Bp = gh; ka = k0; }
    else if (k0 < 4096) { Ap = xb; Bp = gl; ka = k0 - 2048; }
    else                { Ap = xl; Bp = gh; ka = k0 - 4096; }

    __syncthreads();  // all waves done reading previous tile's LDS

#pragma unroll
    for (int it = 0; it < 2; ++it) {
      const int Cb = it * 256 + wave * 64;   // wave-uniform chunk base
      const int C  = Cb + lane;
      const int m  = C >> 3;
      const int jg = (C & 7) ^ (m & 7);      // un-swizzle on global side
      async_cp16(Ap + (size_t)(gm0 + m) * IN_F + ka + jg * 8, &As[Cb * 8]);
    }
#pragma unroll
    for (int it = 0; it < 2; ++it) {
      const int Cb = it * 256 + wave * 64;
      const int C  = Cb + lane;
      const int n  = C >> 3;
      const int jg = (C & 7) ^ (n & 7);
      async_cp16(Bp + (size_t)(gn0 + n) * IN_F + ka + jg * 8, &Bs[Cb * 8]);
    }

    __syncthreads();  // compiler drains vmcnt before s_barrier -> LDS visible

#pragma unroll
    for (int s = 0; s < 2; ++s) {
      bf16x8 af[2], bfr[2];
#pragma unroll
      for (int i = 0; i < 2; ++i) {
        const int m = wm0 + i * 16 + ml;
        const int j = (s * 4 + q) ^ (m & 7);
        af[i] = *(const bf16x8*)&As[(m * 8 + j) * 8];
      }
#pragma unroll
      for (int jn = 0; jn < 2; ++jn) {
        const int n = wn0 + jn * 16 + ml;
        const int j = (s * 4 + q) ^ (n & 7);
        bfr[jn] = *(const bf16x8*)&Bs[(n * 8 + j) * 8];
      }
#pragma unroll
      for (int i = 0; i < 2; ++i)
#pragma unroll
        for (int jn = 0; jn < 2; ++jn)
          acc[i][jn] = __builtin_amdgcn_mfma_f32_16x16x32_bf16(af[i], bfr[jn], acc[i][jn], 0, 0, 0);
    }
  }

  // C/D layout: col=lane&15, row=(lane>>4)*4+reg
#pragma unroll
  for (int i = 0; i < 2; ++i) {
#pragma unroll
    for (int jn = 0; jn < 2; ++jn) {
      const int row = gm0 + wm0 + i * 16 + q * 4;
      const int col = gn0 + wn0 + jn * 16 + ml;
#pragma unroll
      for (int r = 0; r < 4; ++r) {
        if (isgate)
          Gg[(size_t)(row + r) * GATE_N + col] = acc[i][jn][r];
        else
          A2[(size_t)(row + r) * A2C + col] = (bf16)acc[i][jn][r];
      }
    }
  }
}

// bf16 MFMA GEMM (async global_load_lds staging, m97 rung). C = A @ B^T.
// THREE K-segments on absolute k: k<K1 -> (A0,B0); K1<=k<K2 -> (A1,B1) at
// col k-K1; else (A2p,B2p) at col k-K2.
// OUTMODE: 0 = fp32 store, 1 = bf16 store.
// LDS row-major [rows][8 x 16B chunks], chunk pos XOR-swizzled by (row&7).
// XCD-aware chunked blockIdx swizzle (requires nwg % 8 == 0; launches comply).
template <int BM, int BN, int OUTMODE>
__global__ __launch_bounds__(256, 2) void gemm_bt(
    const bf16* __restrict__ A0, int lda0, const bf16* __restrict__ A1, int lda1,
    const bf16* __restrict__ A2p, int lda2,
    const bf16* __restrict__ B0, int ldb0, const bf16* __restrict__ B1, int ldb1,
    const bf16* __restrict__ B2p, int ldb2,
    void* __restrict__ Cout, int ldc, int K1, int K2, int Ktot) {
  constexpr int BK = 64;
  __shared__ __align__(16) bf16 As[BM * BK];
  __shared__ __align__(16) bf16 Bs[BN * BK];

  const int tid  = threadIdx.x;
  const int lane = tid & 63;
  const int ml   = lane & 15;
  const int q    = lane >> 4;
  const int wave = tid >> 6;

  // XCD swizzle: hw block lin%8 ~ XCD id; give each XCD a contiguous chunk.
  const int gx  = gridDim.x;
  const int nwg = gx * gridDim.y;
  int lin = blockIdx.y * gx + blockIdx.x;
  if ((nwg & 7) == 0) lin = (lin & 7) * (nwg >> 3) + (lin >> 3);
  const int gm0 = (lin / gx) * BM;
  const int gn0 = (lin % gx) * BN;

  constexpr int FM = BM / 32;
  constexpr int FN = BN / 32;
  const int wr  = wave >> 1, wc = wave & 1;
  const int wm0 = wr * (BM / 2);
  const int wn0 = wc * (BN / 2);

  f32x4 acc[FM][FN];
  const f32x4 zero = {0.f, 0.f, 0.f, 0.f};
#pragma unroll
  for (int i = 0; i < FM; ++i)
#pragma unroll
    for (int j = 0; j < FN; ++j) acc[i][j] = zero;

  constexpr int NCA = BM * 8 / 256;  // staging instrs per thread (A)
  constexpr int NCB = BN * 8 / 256;

  const int nkt = Ktot / BK;
  for (int kt = 0; kt < nkt; ++kt) {
    const int k0 = kt * BK;
    const bf16* Ap; int lda, ka;
    const bf16* Bp; int ldb, kb;
    if (k0 < K1) {
      Ap = A0;  lda = lda0; ka = k0;      Bp = B0;  ldb = ldb0; kb = k0;
    } else if (k0 < K2) {
      Ap = A1;  lda = lda1; ka = k0 - K1; Bp = B1;  ldb = ldb1; kb = k0 - K1;
    } else {
      Ap = A2p; lda = lda2; ka = k0 - K2; Bp = B2p; ldb = ldb2; kb = k0 - K2;
    }

    __syncthreads();  // all waves done reading previous tile's LDS

#pragma unroll
    for (int it = 0; it < NCA; ++it) {
      const int Cb = it * 256 + wave * 64;   // wave-uniform chunk base
      const int C  = Cb + lane;
      const int m  = C >> 3;
      const int jg = (C & 7) ^ (m & 7);      // un-swizzle on global side
      async_cp16(Ap + (size_t)(gm0 + m) * lda + ka + jg * 8, &As[Cb * 8]);
    }
#pragma unroll
    for (int it = 0; it < NCB; ++it) {
      const int Cb = it * 256 + wave * 64;
      const int C  = Cb + lane;
      const int n  = C >> 3;
      const int jg = (C & 7) ^ (n & 7);
      async_cp16(Bp + (size_t)(gn0 + n) * ldb + kb + jg * 8, &Bs[Cb * 8]);
    }

    __syncthreads();  // compiler drains vmcnt before s_barrier -> LDS visible

#pragma unroll
    for (int s = 0; s < 2; ++s) {
      bf16x8 af[FM], bfr[FN];
#pragma unroll
      for (int i = 0; i < FM; ++i) {
        const int m = wm0 + i * 16 + ml;
        const int j = (s * 4 + q) ^ (m & 7);
        af[i] = *(const bf16x8*)&As[(m * 8 + j) * 8];
      }
#pragma unroll
      for (int jn = 0; jn < FN; ++jn) {
        const int n = wn0 + jn * 16 + ml;
        const int j = (s * 4 + q) ^ (n & 7);
        bfr[jn] = *(const bf16x8*)&Bs[(n * 8 + j) * 8];
      }
#pragma unroll
      for (int i = 0; i < FM; ++i)
#pragma unroll
        for (int jn = 0; jn < FN; ++jn)
          acc[i][jn] = __builtin_amdgcn_mfma_f32_16x16x32_bf16(af[i], bfr[jn], acc[i][jn], 0, 0, 0);
    }
  }

  // C/D layout: col=lane&15, row=(lane>>4)*4+reg
#pragma unroll
  for (int i = 0; i < FM; ++i) {
#pragma unroll
    for (int jn = 0; jn < FN; ++jn) {
      const int row = gm0 + wm0 + i * 16 + q * 4;
      const int col = gn0 + wn0 + jn * 16 + ml;
#pragma unroll
      for (int r = 0; r < 4; ++r) {
        if constexpr (OUTMODE == 1)
          ((bf16*)Cout)[(size_t)(row + r) * ldc + col] = (bf16)acc[i][jn][r];
        else
          ((float*)Cout)[(size_t)(row + r) * ldc + col] = acc[i][jn][r];
      }
    }
  }
}

// One wave per token: fp32 gate logits -> exact top-2 softmax; scale the bf16
// z values already sitting in A2[t][0:256] in-place; fill cols 256..319.
__global__ void router_kernel(const float* __restrict__ Gg, bf16* __restrict__ A2) {
  const int wave = threadIdx.x >> 6, lane = threadIdx.x & 63;
  const int t = blockIdx.x * 4 + wave;
  const float* g = Gg + (size_t)t * 128;
  const float g1 = g[lane], g2 = g[lane + 64];
  float s1 = g1 * g1, s2 = g2 * g2;
#pragma unroll
  for (int off = 1; off < 16; off <<= 1) {
    s1 += __shfl_xor(s1, off, 64);
    s2 += __shfl_xor(s2, off, 64);
  }
  float lg[8];
#pragma unroll
  for (int e = 0; e < 4; ++e) {
    lg[e]     = sqrtf(__shfl(s1, e * 16, 64));
    lg[e + 4] = sqrtf(__shfl(s2, e * 16, 64));
  }
  int i1 = 0; float l1 = lg[0];
#pragma unroll
  for (int e = 1; e < 8; ++e) if (lg[e] > l1) { l1 = lg[e]; i1 = e; }
  int i2 = -1; float l2 = -1e30f;
#pragma unroll
  for (int e = 0; e < 8; ++e) if (e != i1 && lg[e] > l2) { l2 = lg[e]; i2 = e; }
  const float w1 = 1.f / (1.f + expf(l2 - l1));  // exact top-2 softmax renorm
  const float w2 = 1.f - w1;

  bf16* a2 = A2 + (size_t)t * A2C;
#pragma unroll
  for (int c0 = 0; c0 < A2C; c0 += 64) {
    const int c = c0 + lane;
    float v;
    if (c < 256) {
      const int we = c >> 5;
      const float wsel = (we == i1) ? w1 : ((we == i2) ? w2 : 0.f);
      v = (float)a2[c] * wsel;   // z (bf16, written by gatez) scaled in place
    } else if (c < 264) {
      const int we = c - 256;
      v = (we == i1) ? w1 : ((we == i2) ? w2 : 0.f);
    } else if (c == 264) {
      v = 1.f;
    } else {
      v = 0.f;
    }
    a2[c] = (bf16)v;
  }
}

extern "C" void kernel_launch(void* const* d_in, const int* in_sizes, int n_in,
                              void* d_out, int out_size, void* d_ws, size_t ws_size,
                              hipStream_t stream) {
  // size-based dispatch; u/svh share 524288: first = u, second = svh (dict order)
  const float *x = nullptr, *W = nullptr, *b = nullptr, *gw = nullptr;
  const float *u = nullptr, *svh = nullptr, *eb = nullptr;
  int seen524 = 0;
  for (int i = 0; i < n_in; ++i) {
    switch (in_sizes[i]) {
      case 16777216: x  = (const float*)d_in[i]; break;
      case 4194304:  W  = (const float*)d_in[i]; break;
      case 2048:     b  = (const float*)d_in[i]; break;
      case 262144:   gw = (const float*)d_in[i]; break;
      case 524288:   if (seen524++ == 0) u = (const float*)d_in[i];
                     else                svh = (const float*)d_in[i];
                     break;
      case 16384:    eb = (const float*)d_in[i]; break;
      default: break;  // top_k (size 1)
    }
  }
  float* out = (float*)d_out;   // fp32 output (confirmed round 6)

  char* ws = (char*)d_ws;
  bf16*  xb = (bf16*)(ws + WS_XB);
  float* Gg = (float*)(ws + WS_GG);
  bf16*  A2 = (bf16*)(ws + WS_A2);
  bf16*  B2 = (bf16*)(ws + WS_B2);
  bf16*  Wz = (bf16*)(ws + WS_WZ);
  bf16*  Wb = (bf16*)(ws + WS_WB);
  bf16*  xl = (bf16*)(ws + WS_XL);
  bf16*  gh = (bf16*)(ws + WS_GH);
  bf16*  gl = (bf16*)(ws + WS_GL);

  // MFMA split-precision gate needs 88.3 MB of workspace; fall back to the
  // fp32 VALU gate if the harness gave us less (62.6 MB was known-good).
  const bool mfma_gate = (ws_size >= WS_TOTAL_MFMA_GATE);

  prep_kernel<<<1024, 256, 0, stream>>>(x, W, svh, u, eb, b, gw, xb, Wb, Wz, B2,
                                        mfma_gate ? xl : nullptr,
                                        mfma_gate ? gh : nullptr,
                                        mfma_gate ? gl : nullptr);

  if (mfma_gate) {
    // Fused gate (3-segment split-precision, fp32 Gg) + z (bf16 -> A2 cols
    // 0..255). 768 direct-store blocks, no memsets, no atomics.
    gatez_gemm<<<768, 256, 0, stream>>>(xb, xl, gh, gl, Wz, Gg, A2);
  } else {
    // fallback: fp32 VALU gate (memset + atomic) and separate z GEMM
    hipMemsetAsync(Gg, 0, (size_t)T_TOK * GATE_N * 4, stream);
    vgemm_gate<<<dim3(2, T_TOK / 64, GATE_KS), 256, 0, stream>>>(x, gw, Gg);
    gemm_bt<64, 64, 1><<<dim3(Z_COLS / 64, T_TOK / 64), 256, 0, stream>>>(
        xb, IN_F, xb, IN_F, xb, IN_F, Wz, IN_F, Wz, IN_F, Wz, IN_F,
        (void*)A2, A2C, IN_F, IN_F, IN_F);
  }

  router_kernel<<<T_TOK / 4, 256, 0, stream>>>(Gg, A2);

  // out = [xb | A2] @ [Wb | B2]^T  (pre + moe + both biases fused), fp32 store
  gemm_bt<128, 128, 0><<<dim3(OUT_F / 128, T_TOK / 128), 256, 0, stream>>>(
      xb, IN_F, A2, A2C, A2, A2C, Wb, IN_F, B2, A2C, B2, A2C,
      (void*)out, OUT_F, IN_F, K2_TOT, K2_TOT);
}

// Round 4
// 285.138 us; speedup vs baseline: 1.0609x; 1.0609x over previous
//
#include <hip/hip_runtime.h>
#include <cstdint>

typedef __bf16 bf16;
typedef __attribute__((ext_vector_type(8))) __bf16 bf16x8;
typedef __attribute__((ext_vector_type(4))) __bf16 bf16x4;
typedef __attribute__((ext_vector_type(4))) float f32x4;

#define T_TOK 8192
#define IN_F  2048
#define OUT_F 2048
#define GATE_N 128    // E * GK = 8 * 16
#define Z_COLS 256    // svh rows (8 experts x 32)
#define A2C 320       // 256 zw + 8 w + 1 one + 55 zero pad
#define K2_TOT 2368   // 2048 + 320
#define GATE_KS 4     // split-K slices for fp32 gate GEMM (fallback path)
#define UN_N  640     // unified small-GEMM output cols: 256 z + 3*128 gate
#define UN_K  4096    // unified K: [xh | xl]

// ---- workspace layout, UNIFIED path (bytes) ----
#define WS_U_XBL 0                    // bf16 xbl  8192*4096*2 = 67108864  [xh|xl]
#define WS_U_GG  67108864             // fp32 Gg   8192*384*4  = 12582912  (3 components)
#define WS_U_A2  79691776             // bf16 A2   8192*320*2  =  5242880
#define WS_U_B2  84934656             // bf16 B2   2048*320*2  =  1310720
#define WS_U_BZ  86245376             // bf16 Bz   640*4096*2  =  5242880
#define WS_U_WB  91488256             // bf16 Wb   2048*2048*2 =  8388608
#define WS_U_TOTAL 99876864ULL

// ---- workspace layout, FALLBACK path (known-good 53.7 MB) ----
#define WS_F_XB  0
#define WS_F_GG  33554432
#define WS_F_A2  37748736
#define WS_F_B2  42991616
#define WS_F_WZ  44302336
#define WS_F_WB  45350912

// async 16B global->LDS; LDS dest is wave-uniform base, HW scatters lane i at
// base + i*16 (m104/m108). R1-proven incantation.
__device__ __forceinline__ void async_cp16(const bf16* g, bf16* l) {
  __builtin_amdgcn_global_load_lds(
      (const __attribute__((address_space(1))) void*)reinterpret_cast<uintptr_t>(g),
      (__attribute__((address_space(3))) void*)(uint32_t)reinterpret_cast<uintptr_t>(l),
      16, 0, 0);
}

// Convert fp32 inputs to bf16 workspace tensors.
// unified=1: xout = xbl[8192][4096] rows [xh | xl] (lo half = bf16 residual);
//            WzBz = Bz[640][4096] = rows [Wz|0; gh|0; gl|0; 0|gh].
// unified=0: xout = xb[8192][2048] (hi only); WzBz = Wz[256][2048].
__global__ void prep_kernel(const float* __restrict__ x, const float* __restrict__ W,
                            const float* __restrict__ svh,
                            const float* __restrict__ u, const float* __restrict__ eb,
                            const float* __restrict__ b, const float* __restrict__ gw,
                            bf16* __restrict__ xout, bf16* __restrict__ Wb,
                            bf16* __restrict__ WzBz, bf16* __restrict__ B2,
                            int unified) {
  const int idx = blockIdx.x * 256 + threadIdx.x;
  const int nt  = gridDim.x * 256;

  const int nx4 = (T_TOK * IN_F) / 4;
  for (int i = idx; i < nx4; i += nt) {
    const float4 v = ((const float4*)x)[i];
    bf16x4 o = {(bf16)v.x, (bf16)v.y, (bf16)v.z, (bf16)v.w};
    if (unified) {
      const int t = i >> 9;            // 512 float4 per 2048-wide row
      const int c = (i & 511) << 2;
      *(bf16x4*)&xout[(size_t)t * UN_K + c] = o;
      bf16x4 l = {(bf16)(v.x - (float)o.x), (bf16)(v.y - (float)o.y),
                  (bf16)(v.z - (float)o.z), (bf16)(v.w - (float)o.w)};
      *(bf16x4*)&xout[(size_t)t * UN_K + IN_F + c] = l;
    } else {
      *(bf16x4*)&xout[(size_t)i * 4] = o;
    }
  }

  const int nw4 = (OUT_F * IN_F) / 4;
  for (int i = idx; i < nw4; i += nt) {
    const float4 v = ((const float4*)W)[i];
    bf16x4 o = {(bf16)v.x, (bf16)v.y, (bf16)v.z, (bf16)v.w};
    *(bf16x4*)&Wb[(size_t)i * 4] = o;
  }

  if (unified) {
    // Bz[640][4096]: r<256 -> [svh_r | 0]; 256..383 -> [gh_{r-256} | 0];
    // 384..511 -> [gl_{r-384} | 0]; 512..639 -> [0 | gh_{r-512}]
    const int nbz4 = UN_N * (UN_K / 4);
    for (int i = idx; i < nbz4; i += nt) {
      const int r  = i >> 10;          // 1024 float4 per 4096-wide row
      const int jc = (i & 1023) << 2;
      bf16x4 o = {(bf16)0.f, (bf16)0.f, (bf16)0.f, (bf16)0.f};
      if (r < 256) {
        if (jc < IN_F) {
          const float4 v = *(const float4*)(svh + (size_t)r * IN_F + jc);
          o = bf16x4{(bf16)v.x, (bf16)v.y, (bf16)v.z, (bf16)v.w};
        }
      } else if (r < 384) {
        if (jc < IN_F) {
          const float4 v = *(const float4*)(gw + (size_t)(r - 256) * IN_F + jc);
          o = bf16x4{(bf16)v.x, (bf16)v.y, (bf16)v.z, (bf16)v.w};
        }
      } else if (r < 512) {
        if (jc < IN_F) {
          const float4 v = *(const float4*)(gw + (size_t)(r - 384) * IN_F + jc);
          bf16x4 h = {(bf16)v.x, (bf16)v.y, (bf16)v.z, (bf16)v.w};
          o = bf16x4{(bf16)(v.x - (float)h.x), (bf16)(v.y - (float)h.y),
                     (bf16)(v.z - (float)h.z), (bf16)(v.w - (float)h.w)};
        }
      } else {
        if (jc >= IN_F) {
          const float4 v = *(const float4*)(gw + (size_t)(r - 512) * IN_F + (jc - IN_F));
          o = bf16x4{(bf16)v.x, (bf16)v.y, (bf16)v.z, (bf16)v.w};
        }
      }
      *(bf16x4*)&WzBz[(size_t)i * 4] = o;
    }
  } else {
    const int nz4 = (Z_COLS * IN_F) / 4;   // svh flat [256][2048]
    for (int i = idx; i < nz4; i += nt) {
      const float4 v = ((const float4*)svh)[i];
      bf16x4 o = {(bf16)v.x, (bf16)v.y, (bf16)v.z, (bf16)v.w};
      *(bf16x4*)&WzBz[(size_t)i * 4] = o;
    }
  }

  // B2[o][j]: j<256 -> u[e=j>>5][o][k=j&31]; 256..263 -> eb[j-256][o]; 264 -> b[o]; else 0
  for (int i = idx; i < OUT_F * A2C; i += nt) {
    const int o = i / A2C, j = i - o * A2C;
    float v;
    if (j < 256) {
      const int e = j >> 5, k = j & 31;
      v = u[((size_t)(e * OUT_F + o)) * 32 + k];
    } else if (j < 264) {
      v = eb[(size_t)(j - 256) * OUT_F + o];
    } else if (j == 264) {
      v = b[o];
    } else {
      v = 0.f;
    }
    B2[i] = (bf16)v;
  }
}

// fp32 VALU gate GEMM fallback (only used if ws_size can't fit the unified
// buffers). Split-K x4 (blockIdx.z), atomicAdd epilogue into zeroed Gg.
__global__ __launch_bounds__(256) void vgemm_gate(
    const float* __restrict__ x, const float* __restrict__ gw,
    float* __restrict__ Gg) {
  __shared__ float As[64][37];
  __shared__ float Bs[64][37];
  const int tid = threadIdx.x;
  const int tx = tid & 15, ty = tid >> 4;
  const int gm0 = blockIdx.y * 64, gn0 = blockIdx.x * 64;
  const int kbeg = blockIdx.z * (IN_F / GATE_KS);
  const int kend = kbeg + (IN_F / GATE_KS);

  float acc[4][4] = {};
  for (int k0 = kbeg; k0 < kend; k0 += 32) {
    __syncthreads();
#pragma unroll
    for (int it = 0; it < 2; ++it) {
      const int idx = it * 256 + tid;
      const int r = idx >> 3, c4 = (idx & 7) * 4;
      const float4 av = *(const float4*)(x + (size_t)(gm0 + r) * IN_F + k0 + c4);
      As[r][c4 + 0] = av.x; As[r][c4 + 1] = av.y;
      As[r][c4 + 2] = av.z; As[r][c4 + 3] = av.w;
      const float4 bv = *(const float4*)(gw + (size_t)(gn0 + r) * IN_F + k0 + c4);
      Bs[r][c4 + 0] = bv.x; Bs[r][c4 + 1] = bv.y;
      Bs[r][c4 + 2] = bv.z; Bs[r][c4 + 3] = bv.w;
    }
    __syncthreads();
#pragma unroll 4
    for (int k = 0; k < 32; ++k) {
      float a[4], bb[4];
#pragma unroll
      for (int i = 0; i < 4; ++i) a[i] = As[4 * ty + i][k];
#pragma unroll
      for (int j = 0; j < 4; ++j) bb[j] = Bs[4 * tx + j][k];
#pragma unroll
      for (int i = 0; i < 4; ++i)
#pragma unroll
        for (int j = 0; j < 4; ++j) acc[i][j] += a[i] * bb[j];
    }
  }
#pragma unroll
  for (int i = 0; i < 4; ++i)
#pragma unroll
    for (int j = 0; j < 4; ++j)
      atomicAdd(&Gg[(size_t)(gm0 + 4 * ty + i) * 128 + (gn0 + 4 * tx + j)],
                acc[i][j]);
}

// bf16 MFMA GEMM (async global_load_lds staging, m97 rung). C = A @ B^T.
// THREE K-segments on absolute k: k<K1 -> (A0,B0); K1<=k<K2 -> (A1,B1) at
// col k-K1; else (A2p,B2p) at col k-K2.
// OUTMODE: 0 = fp32 store, 1 = bf16 store,
//          3 = split store: col<nsplit -> bf16 to CoutB (ldcB);
//              col>=nsplit -> fp32 to Cout at col-nsplit (ldc).
// LDS row-major [rows][8 x 16B chunks], chunk pos XOR-swizzled by (row&7).
// XCD-aware chunked blockIdx swizzle (requires nwg % 8 == 0; launches comply).
template <int BM, int BN, int OUTMODE>
__global__ __launch_bounds__(256, 2) void gemm_bt(
    const bf16* __restrict__ A0, int lda0, const bf16* __restrict__ A1, int lda1,
    const bf16* __restrict__ A2p, int lda2,
    const bf16* __restrict__ B0, int ldb0, const bf16* __restrict__ B1, int ldb1,
    const bf16* __restrict__ B2p, int ldb2,
    void* __restrict__ Cout, int ldc,
    void* __restrict__ CoutB, int ldcB, int nsplit,
    int K1, int K2, int Ktot) {
  constexpr int BK = 64;
  __shared__ __align__(16) bf16 As[BM * BK];
  __shared__ __align__(16) bf16 Bs[BN * BK];

  const int tid  = threadIdx.x;
  const int lane = tid & 63;
  const int ml   = lane & 15;
  const int q    = lane >> 4;
  const int wave = tid >> 6;

  // XCD swizzle: hw block lin%8 ~ XCD id; give each XCD a contiguous chunk.
  const int gx  = gridDim.x;
  const int nwg = gx * gridDim.y;
  int lin = blockIdx.y * gx + blockIdx.x;
  if ((nwg & 7) == 0) lin = (lin & 7) * (nwg >> 3) + (lin >> 3);
  const int gm0 = (lin / gx) * BM;
  const int gn0 = (lin % gx) * BN;

  constexpr int FM = BM / 32;
  constexpr int FN = BN / 32;
  const int wr  = wave >> 1, wc = wave & 1;
  const int wm0 = wr * (BM / 2);
  const int wn0 = wc * (BN / 2);

  f32x4 acc[FM][FN];
  const f32x4 zero = {0.f, 0.f, 0.f, 0.f};
#pragma unroll
  for (int i = 0; i < FM; ++i)
#pragma unroll
    for (int j = 0; j < FN; ++j) acc[i][j] = zero;

  constexpr int NCA = BM * 8 / 256;  // staging instrs per thread (A)
  constexpr int NCB = BN * 8 / 256;

  const int nkt = Ktot / BK;
  for (int kt = 0; kt < nkt; ++kt) {
    const int k0 = kt * BK;
    const bf16* Ap; int lda, ka;
    const bf16* Bp; int ldb, kb;
    if (k0 < K1) {
      Ap = A0;  lda = lda0; ka = k0;      Bp = B0;  ldb = ldb0; kb = k0;
    } else if (k0 < K2) {
      Ap = A1;  lda = lda1; ka = k0 - K1; Bp = B1;  ldb = ldb1; kb = k0 - K1;
    } else {
      Ap = A2p; lda = lda2; ka = k0 - K2; Bp = B2p; ldb = ldb2; kb = k0 - K2;
    }

    __syncthreads();  // all waves done reading previous tile's LDS

#pragma unroll
    for (int it = 0; it < NCA; ++it) {
      const int Cb = it * 256 + wave * 64;   // wave-uniform chunk base
      const int C  = Cb + lane;
      const int m  = C >> 3;
      const int jg = (C & 7) ^ (m & 7);      // un-swizzle on global side
      async_cp16(Ap + (size_t)(gm0 + m) * lda + ka + jg * 8, &As[Cb * 8]);
    }
#pragma unroll
    for (int it = 0; it < NCB; ++it) {
      const int Cb = it * 256 + wave * 64;
      const int C  = Cb + lane;
      const int n  = C >> 3;
      const int jg = (C & 7) ^ (n & 7);
      async_cp16(Bp + (size_t)(gn0 + n) * ldb + kb + jg * 8, &Bs[Cb * 8]);
    }

    __syncthreads();  // compiler drains vmcnt before s_barrier -> LDS visible

#pragma unroll
    for (int s = 0; s < 2; ++s) {
      bf16x8 af[FM], bfr[FN];
#pragma unroll
      for (int i = 0; i < FM; ++i) {
        const int m = wm0 + i * 16 + ml;
        const int j = (s * 4 + q) ^ (m & 7);
        af[i] = *(const bf16x8*)&As[(m * 8 + j) * 8];
      }
#pragma unroll
      for (int jn = 0; jn < FN; ++jn) {
        const int n = wn0 + jn * 16 + ml;
        const int j = (s * 4 + q) ^ (n & 7);
        bfr[jn] = *(const bf16x8*)&Bs[(n * 8 + j) * 8];
      }
#pragma unroll
      for (int i = 0; i < FM; ++i)
#pragma unroll
        for (int jn = 0; jn < FN; ++jn)
          acc[i][jn] = __builtin_amdgcn_mfma_f32_16x16x32_bf16(af[i], bfr[jn], acc[i][jn], 0, 0, 0);
    }
  }

  // C/D layout: col=lane&15, row=(lane>>4)*4+reg
#pragma unroll
  for (int i = 0; i < FM; ++i) {
#pragma unroll
    for (int jn = 0; jn < FN; ++jn) {
      const int row = gm0 + wm0 + i * 16 + q * 4;
      const int col = gn0 + wn0 + jn * 16 + ml;
#pragma unroll
      for (int r = 0; r < 4; ++r) {
        if constexpr (OUTMODE == 1) {
          ((bf16*)Cout)[(size_t)(row + r) * ldc + col] = (bf16)acc[i][jn][r];
        } else if constexpr (OUTMODE == 3) {
          if (col < nsplit)
            ((bf16*)CoutB)[(size_t)(row + r) * ldcB + col] = (bf16)acc[i][jn][r];
          else
            ((float*)Cout)[(size_t)(row + r) * ldc + (col - nsplit)] = acc[i][jn][r];
        } else {
          ((float*)Cout)[(size_t)(row + r) * ldc + col] = acc[i][jn][r];
        }
      }
    }
  }
}

// One wave per token: fp32 gate logits (sum of ncomp 128-wide components in a
// gld-wide Gg row) -> exact top-2 softmax; scale the bf16 z values already
// sitting in A2[t][0:256] in-place; fill cols 256..319.
__global__ void router_kernel(const float* __restrict__ Gg, bf16* __restrict__ A2,
                              int gld, int ncomp) {
  const int wave = threadIdx.x >> 6, lane = threadIdx.x & 63;
  const int t = blockIdx.x * 4 + wave;
  const float* g = Gg + (size_t)t * gld;
  float g1 = 0.f, g2 = 0.f;
  for (int cc = 0; cc < ncomp; ++cc) {
    g1 += g[cc * 128 + lane];
    g2 += g[cc * 128 + 64 + lane];
  }
  float s1 = g1 * g1, s2 = g2 * g2;
#pragma unroll
  for (int off = 1; off < 16; off <<= 1) {
    s1 += __shfl_xor(s1, off, 64);
    s2 += __shfl_xor(s2, off, 64);
  }
  float lg[8];
#pragma unroll
  for (int e = 0; e < 4; ++e) {
    lg[e]     = sqrtf(__shfl(s1, e * 16, 64));
    lg[e + 4] = sqrtf(__shfl(s2, e * 16, 64));
  }
  int i1 = 0; float l1 = lg[0];
#pragma unroll
  for (int e = 1; e < 8; ++e) if (lg[e] > l1) { l1 = lg[e]; i1 = e; }
  int i2 = -1; float l2 = -1e30f;
#pragma unroll
  for (int e = 0; e < 8; ++e) if (e != i1 && lg[e] > l2) { l2 = lg[e]; i2 = e; }
  const float w1 = 1.f / (1.f + expf(l2 - l1));  // exact top-2 softmax renorm
  const float w2 = 1.f - w1;

  bf16* a2 = A2 + (size_t)t * A2C;
#pragma unroll
  for (int c0 = 0; c0 < A2C; c0 += 64) {
    const int c = c0 + lane;
    float v;
    if (c < 256) {
      const int we = c >> 5;
      const float wsel = (we == i1) ? w1 : ((we == i2) ? w2 : 0.f);
      v = (float)a2[c] * wsel;   // z (bf16, written by unified GEMM) scaled in place
    } else if (c < 264) {
      const int we = c - 256;
      v = (we == i1) ? w1 : ((we == i2) ? w2 : 0.f);
    } else if (c == 264) {
      v = 1.f;
    } else {
      v = 0.f;
    }
    a2[c] = (bf16)v;
  }
}

extern "C" void kernel_launch(void* const* d_in, const int* in_sizes, int n_in,
                              void* d_out, int out_size, void* d_ws, size_t ws_size,
                              hipStream_t stream) {
  // size-based dispatch; u/svh share 524288: first = u, second = svh (dict order)
  const float *x = nullptr, *W = nullptr, *b = nullptr, *gw = nullptr;
  const float *u = nullptr, *svh = nullptr, *eb = nullptr;
  int seen524 = 0;
  for (int i = 0; i < n_in; ++i) {
    switch (in_sizes[i]) {
      case 16777216: x  = (const float*)d_in[i]; break;
      case 4194304:  W  = (const float*)d_in[i]; break;
      case 2048:     b  = (const float*)d_in[i]; break;
      case 262144:   gw = (const float*)d_in[i]; break;
      case 524288:   if (seen524++ == 0) u = (const float*)d_in[i];
                     else                svh = (const float*)d_in[i];
                     break;
      case 16384:    eb = (const float*)d_in[i]; break;
      default: break;  // top_k (size 1)
    }
  }
  float* out = (float*)d_out;   // fp32 output (confirmed round 6)

  char* ws = (char*)d_ws;
  // Unified path needs 99.9 MB; fall back to the known-good 53.7 MB layout
  // with the fp32 VALU gate if the harness gave us less.
  const bool unified = (ws_size >= WS_U_TOTAL);

  if (unified) {
    bf16*  xbl = (bf16*)(ws + WS_U_XBL);
    float* Gg  = (float*)(ws + WS_U_GG);
    bf16*  A2  = (bf16*)(ws + WS_U_A2);
    bf16*  B2  = (bf16*)(ws + WS_U_B2);
    bf16*  Bz  = (bf16*)(ws + WS_U_BZ);
    bf16*  Wb  = (bf16*)(ws + WS_U_WB);

    prep_kernel<<<1024, 256, 0, stream>>>(x, W, svh, u, eb, b, gw,
                                          xbl, Wb, Bz, B2, 1);

    // Unified small GEMM: [xh|xl] @ Bz^T (K=4096, N=640).
    //   cols 0..255   = z = xh@Wz^T          -> bf16 A2[.][0:256]
    //   cols 256..383 = xh@gh^T  (comp 0) \
    //   cols 384..511 = xh@gl^T  (comp 1)  -> fp32 Gg[.][0:384]
    //   cols 512..639 = xl@gh^T  (comp 2) /
    // 640 blocks of 128x64 tiles; direct stores, no atomics, no memsets.
    gemm_bt<128, 64, 3><<<dim3(UN_N / 64, T_TOK / 128), 256, 0, stream>>>(
        xbl, UN_K, xbl, UN_K, xbl, UN_K,
        Bz, UN_K, Bz, UN_K, Bz, UN_K,
        (void*)Gg, 384, (void*)A2, A2C, Z_COLS,
        UN_K, UN_K, UN_K);

    router_kernel<<<T_TOK / 4, 256, 0, stream>>>(Gg, A2, 384, 3);

    // out = [xh | A2] @ [Wb | B2]^T (pre + moe + both biases), fp32 store.
    // xh read straight from xbl via lda=4096 (segment 0 only touches k<2048).
    gemm_bt<128, 128, 0><<<dim3(OUT_F / 128, T_TOK / 128), 256, 0, stream>>>(
        xbl, UN_K, A2, A2C, A2, A2C, Wb, IN_F, B2, A2C, B2, A2C,
        (void*)out, OUT_F, nullptr, 0, 0,
        IN_F, K2_TOT, K2_TOT);
  } else {
    bf16*  xb = (bf16*)(ws + WS_F_XB);
    float* Gg = (float*)(ws + WS_F_GG);
    bf16*  A2 = (bf16*)(ws + WS_F_A2);
    bf16*  B2 = (bf16*)(ws + WS_F_B2);
    bf16*  Wz = (bf16*)(ws + WS_F_WZ);
    bf16*  Wb = (bf16*)(ws + WS_F_WB);

    prep_kernel<<<1024, 256, 0, stream>>>(x, W, svh, u, eb, b, gw,
                                          xb, Wb, Wz, B2, 0);

    hipMemsetAsync(Gg, 0, (size_t)T_TOK * GATE_N * 4, stream);
    vgemm_gate<<<dim3(2, T_TOK / 64, GATE_KS), 256, 0, stream>>>(x, gw, Gg);
    gemm_bt<64, 64, 1><<<dim3(Z_COLS / 64, T_TOK / 64), 256, 0, stream>>>(
        xb, IN_F, xb, IN_F, xb, IN_F, Wz, IN_F, Wz, IN_F, Wz, IN_F,
        (void*)A2, A2C, nullptr, 0, 0, IN_F, IN_F, IN_F);

    router_kernel<<<T_TOK / 4, 256, 0, stream>>>(Gg, A2, 128, 1);

    gemm_bt<128, 128, 0><<<dim3(OUT_F / 128, T_TOK / 128), 256, 0, stream>>>(
        xb, IN_F, A2, A2C, A2, A2C, Wb, IN_F, B2, A2C, B2, A2C,
        (void*)out, OUT_F, nullptr, 0, 0,
        IN_F, K2_TOT, K2_TOT);
  }
}

// Round 5
// 267.257 us; speedup vs baseline: 1.1319x; 1.0669x over previous
//
#include <hip/hip_runtime.h>
#include <cstdint>

typedef __bf16 bf16;
typedef __attribute__((ext_vector_type(8))) __bf16 bf16x8;
typedef __attribute__((ext_vector_type(4))) __bf16 bf16x4;
typedef __attribute__((ext_vector_type(4))) float f32x4;

#define T_TOK 8192
#define IN_F  2048
#define OUT_F 2048
#define GATE_N 128    // E * GK = 8 * 16
#define Z_COLS 256    // svh rows (8 experts x 32)
#define A2C 320       // 256 zw + 8 w + 1 one + 55 zero pad
#define K2_TOT 2368   // 2048 + 320
#define GATE_KS 4     // split-K slices for fp32 gate GEMM (fallback path)
#define UN_N  640     // small-GEMM output cols: 256 z + 3*128 gate comps
#define BP_R  512     // packed B rows: 256 Wz + 128 gh + 128 gl
#define XBL_LD 4096   // xbl row stride: [xh | xl]

// ---- workspace layout, UNIFIED path (bytes) ----
#define WS_U_XBL 0                    // bf16 xbl  8192*4096*2 = 67108864  [xh|xl]
#define WS_U_GG  67108864             // fp32 Gg   8192*384*4  = 12582912  (3 components)
#define WS_U_A2  79691776             // bf16 A2   8192*320*2  =  5242880
#define WS_U_B2  84934656             // bf16 B2   2048*320*2  =  1310720
#define WS_U_BP  86245376             // bf16 Bp   512*2048*2  =  2097152
#define WS_U_WB  88342528             // bf16 Wb   2048*2048*2 =  8388608
#define WS_U_TOTAL 96731136ULL

// ---- workspace layout, FALLBACK path (known-good 53.7 MB) ----
#define WS_F_XB  0
#define WS_F_GG  33554432
#define WS_F_A2  37748736
#define WS_F_B2  42991616
#define WS_F_WZ  44302336
#define WS_F_WB  45350912

// async 16B global->LDS; LDS dest is wave-uniform base, HW scatters lane i at
// base + i*16 (m104/m108). R1-proven incantation.
__device__ __forceinline__ void async_cp16(const bf16* g, bf16* l) {
  __builtin_amdgcn_global_load_lds(
      (const __attribute__((address_space(1))) void*)reinterpret_cast<uintptr_t>(g),
      (__attribute__((address_space(3))) void*)(uint32_t)reinterpret_cast<uintptr_t>(l),
      16, 0, 0);
}

// Convert fp32 inputs to bf16 workspace tensors.
// unified=1: xout = xbl[8192][4096] rows [xh | xl] (lo half = bf16 residual);
//            WzBp = Bp[512][2048] = rows [Wz; gh; gl] (no padding).
// unified=0: xout = xb[8192][2048] (hi only); WzBp = Wz[256][2048].
__global__ void prep_kernel(const float* __restrict__ x, const float* __restrict__ W,
                            const float* __restrict__ svh,
                            const float* __restrict__ u, const float* __restrict__ eb,
                            const float* __restrict__ b, const float* __restrict__ gw,
                            bf16* __restrict__ xout, bf16* __restrict__ Wb,
                            bf16* __restrict__ WzBp, bf16* __restrict__ B2,
                            int unified) {
  const int idx = blockIdx.x * 256 + threadIdx.x;
  const int nt  = gridDim.x * 256;

  const int nx4 = (T_TOK * IN_F) / 4;
  for (int i = idx; i < nx4; i += nt) {
    const float4 v = ((const float4*)x)[i];
    bf16x4 o = {(bf16)v.x, (bf16)v.y, (bf16)v.z, (bf16)v.w};
    if (unified) {
      const int t = i >> 9;            // 512 float4 per 2048-wide row
      const int c = (i & 511) << 2;
      *(bf16x4*)&xout[(size_t)t * XBL_LD + c] = o;
      bf16x4 l = {(bf16)(v.x - (float)o.x), (bf16)(v.y - (float)o.y),
                  (bf16)(v.z - (float)o.z), (bf16)(v.w - (float)o.w)};
      *(bf16x4*)&xout[(size_t)t * XBL_LD + IN_F + c] = l;
    } else {
      *(bf16x4*)&xout[(size_t)i * 4] = o;
    }
  }

  const int nw4 = (OUT_F * IN_F) / 4;
  for (int i = idx; i < nw4; i += nt) {
    const float4 v = ((const float4*)W)[i];
    bf16x4 o = {(bf16)v.x, (bf16)v.y, (bf16)v.z, (bf16)v.w};
    *(bf16x4*)&Wb[(size_t)i * 4] = o;
  }

  if (unified) {
    // Bp[512][2048]: r<256 -> svh_r; 256..383 -> gh_{r-256}; 384..511 -> gl_{r-384}
    const int nbp4 = BP_R * (IN_F / 4);
    for (int i = idx; i < nbp4; i += nt) {
      const int r  = i >> 9;           // 512 float4 per 2048-wide row
      const int jc = (i & 511) << 2;
      bf16x4 o;
      if (r < 256) {
        const float4 v = *(const float4*)(svh + (size_t)r * IN_F + jc);
        o = bf16x4{(bf16)v.x, (bf16)v.y, (bf16)v.z, (bf16)v.w};
      } else if (r < 384) {
        const float4 v = *(const float4*)(gw + (size_t)(r - 256) * IN_F + jc);
        o = bf16x4{(bf16)v.x, (bf16)v.y, (bf16)v.z, (bf16)v.w};
      } else {
        const float4 v = *(const float4*)(gw + (size_t)(r - 384) * IN_F + jc);
        bf16x4 h = {(bf16)v.x, (bf16)v.y, (bf16)v.z, (bf16)v.w};
        o = bf16x4{(bf16)(v.x - (float)h.x), (bf16)(v.y - (float)h.y),
                   (bf16)(v.z - (float)h.z), (bf16)(v.w - (float)h.w)};
      }
      *(bf16x4*)&WzBp[(size_t)i * 4] = o;
    }
  } else {
    const int nz4 = (Z_COLS * IN_F) / 4;   // svh flat [256][2048]
    for (int i = idx; i < nz4; i += nt) {
      const float4 v = ((const float4*)svh)[i];
      bf16x4 o = {(bf16)v.x, (bf16)v.y, (bf16)v.z, (bf16)v.w};
      *(bf16x4*)&WzBp[(size_t)i * 4] = o;
    }
  }

  // B2[o][j]: j<256 -> u[e=j>>5][o][k=j&31]; 256..263 -> eb[j-256][o]; 264 -> b[o]; else 0
  for (int i = idx; i < OUT_F * A2C; i += nt) {
    const int o = i / A2C, j = i - o * A2C;
    float v;
    if (j < 256) {
      const int e = j >> 5, k = j & 31;
      v = u[((size_t)(e * OUT_F + o)) * 32 + k];
    } else if (j < 264) {
      v = eb[(size_t)(j - 256) * OUT_F + o];
    } else if (j == 264) {
      v = b[o];
    } else {
      v = 0.f;
    }
    B2[i] = (bf16)v;
  }
}

// fp32 VALU gate GEMM fallback (only used if ws_size can't fit the unified
// buffers). Split-K x4 (blockIdx.z), atomicAdd epilogue into zeroed Gg.
__global__ __launch_bounds__(256) void vgemm_gate(
    const float* __restrict__ x, const float* __restrict__ gw,
    float* __restrict__ Gg) {
  __shared__ float As[64][37];
  __shared__ float Bs[64][37];
  const int tid = threadIdx.x;
  const int tx = tid & 15, ty = tid >> 4;
  const int gm0 = blockIdx.y * 64, gn0 = blockIdx.x * 64;
  const int kbeg = blockIdx.z * (IN_F / GATE_KS);
  const int kend = kbeg + (IN_F / GATE_KS);

  float acc[4][4] = {};
  for (int k0 = kbeg; k0 < kend; k0 += 32) {
    __syncthreads();
#pragma unroll
    for (int it = 0; it < 2; ++it) {
      const int idx = it * 256 + tid;
      const int r = idx >> 3, c4 = (idx & 7) * 4;
      const float4 av = *(const float4*)(x + (size_t)(gm0 + r) * IN_F + k0 + c4);
      As[r][c4 + 0] = av.x; As[r][c4 + 1] = av.y;
      As[r][c4 + 2] = av.z; As[r][c4 + 3] = av.w;
      const float4 bv = *(const float4*)(gw + (size_t)(gn0 + r) * IN_F + k0 + c4);
      Bs[r][c4 + 0] = bv.x; Bs[r][c4 + 1] = bv.y;
      Bs[r][c4 + 2] = bv.z; Bs[r][c4 + 3] = bv.w;
    }
    __syncthreads();
#pragma unroll 4
    for (int k = 0; k < 32; ++k) {
      float a[4], bb[4];
#pragma unroll
      for (int i = 0; i < 4; ++i) a[i] = As[4 * ty + i][k];
#pragma unroll
      for (int j = 0; j < 4; ++j) bb[j] = Bs[4 * tx + j][k];
#pragma unroll
      for (int i = 0; i < 4; ++i)
#pragma unroll
        for (int j = 0; j < 4; ++j) acc[i][j] += a[i] * bb[j];
    }
  }
#pragma unroll
  for (int i = 0; i < 4; ++i)
#pragma unroll
    for (int j = 0; j < 4; ++j)
      atomicAdd(&Gg[(size_t)(gm0 + 4 * ty + i) * 128 + (gn0 + 4 * tx + j)],
                acc[i][j]);
}

// Uniform small GEMM: C[8192][640] tiles of 128x64, ALL with K=2048.
// Per-block operand select by output column group (no padding, no imbalance):
//   cols   0..255 : A=xh, B=Bp rows n0      (Wz)  -> bf16 A2[.][col]
//   cols 256..383 : A=xh, B=Bp rows n0      (gh)  -> fp32 Gg[.][col-256]
//   cols 384..511 : A=xh, B=Bp rows n0      (gl)  -> fp32 Gg[.][col-256]
//   cols 512..639 : A=xl, B=Bp rows n0-256  (gh)  -> fp32 Gg[.][col-256]
// xh/xl live in xbl[8192][4096] as [xh|xl]; xl = column offset 2048.
// m97 inner structure (async_cp16 staging, XOR swizzle); XCD-chunked swizzle.
__global__ __launch_bounds__(256, 2) void uni_gemm(
    const bf16* __restrict__ xbl, const bf16* __restrict__ Bp,
    float* __restrict__ Gg, bf16* __restrict__ A2) {
  constexpr int BM = 128, BN = 64, BK = 64;
  __shared__ __align__(16) bf16 As[BM * BK];
  __shared__ __align__(16) bf16 Bs[BN * BK];

  const int tid  = threadIdx.x;
  const int lane = tid & 63;
  const int ml   = lane & 15;
  const int q    = lane >> 4;
  const int wave = tid >> 6;

  // grid = 640 blocks (10 col-blocks x 64 row-blocks); 640 % 8 == 0.
  int lin = blockIdx.x;
  lin = (lin & 7) * 80 + (lin >> 3);          // XCD-chunked swizzle
  const int gm0 = (lin / 10) * BM;
  const int n0  = (lin % 10) * BN;            // global output col base
  const int aoff  = (n0 >= 512) ? IN_F : 0;   // xl half for comp-3
  const int brow0 = (n0 >= 512) ? n0 - 256 : n0;

  const int wr = wave >> 1, wc = wave & 1;
  const int wm0 = wr * 64, wn0 = wc * 32;

  f32x4 acc[4][2];
  const f32x4 zero = {0.f, 0.f, 0.f, 0.f};
#pragma unroll
  for (int i = 0; i < 4; ++i)
#pragma unroll
    for (int j = 0; j < 2; ++j) acc[i][j] = zero;

  for (int kt = 0; kt < IN_F / BK; ++kt) {
    const int k0 = kt * BK;

    __syncthreads();  // all waves done reading previous tile's LDS

#pragma unroll
    for (int it = 0; it < 4; ++it) {          // A: 128 rows * 8 chunks / 256
      const int Cb = it * 256 + wave * 64;
      const int C  = Cb + lane;
      const int m  = C >> 3;
      const int jg = (C & 7) ^ (m & 7);
      async_cp16(xbl + (size_t)(gm0 + m) * XBL_LD + aoff + k0 + jg * 8, &As[Cb * 8]);
    }
#pragma unroll
    for (int it = 0; it < 2; ++it) {          // B: 64 rows * 8 chunks / 256
      const int Cb = it * 256 + wave * 64;
      const int C  = Cb + lane;
      const int n  = C >> 3;
      const int jg = (C & 7) ^ (n & 7);
      async_cp16(Bp + (size_t)(brow0 + n) * IN_F + k0 + jg * 8, &Bs[Cb * 8]);
    }

    __syncthreads();  // compiler drains vmcnt before s_barrier -> LDS visible

#pragma unroll
    for (int s = 0; s < 2; ++s) {
      bf16x8 af[4], bfr[2];
#pragma unroll
      for (int i = 0; i < 4; ++i) {
        const int m = wm0 + i * 16 + ml;
        const int j = (s * 4 + q) ^ (m & 7);
        af[i] = *(const bf16x8*)&As[(m * 8 + j) * 8];
      }
#pragma unroll
      for (int jn = 0; jn < 2; ++jn) {
        const int n = wn0 + jn * 16 + ml;
        const int j = (s * 4 + q) ^ (n & 7);
        bfr[jn] = *(const bf16x8*)&Bs[(n * 8 + j) * 8];
      }
#pragma unroll
      for (int i = 0; i < 4; ++i)
#pragma unroll
        for (int jn = 0; jn < 2; ++jn)
          acc[i][jn] = __builtin_amdgcn_mfma_f32_16x16x32_bf16(af[i], bfr[jn], acc[i][jn], 0, 0, 0);
    }
  }

  // C/D layout: col=lane&15, row=(lane>>4)*4+reg. n0 group is block-uniform.
#pragma unroll
  for (int i = 0; i < 4; ++i) {
#pragma unroll
    for (int jn = 0; jn < 2; ++jn) {
      const int row = gm0 + wm0 + i * 16 + q * 4;
      const int col = n0 + wn0 + jn * 16 + ml;
#pragma unroll
      for (int r = 0; r < 4; ++r) {
        if (n0 < 256)
          A2[(size_t)(row + r) * A2C + col] = (bf16)acc[i][jn][r];
        else
          Gg[(size_t)(row + r) * 384 + (col - 256)] = acc[i][jn][r];
      }
    }
  }
}

// bf16 MFMA GEMM (async global_load_lds staging, m97 rung). C = A @ B^T.
// THREE K-segments on absolute k: k<K1 -> (A0,B0); K1<=k<K2 -> (A1,B1) at
// col k-K1; else (A2p,B2p) at col k-K2.
// OUTMODE: 0 = fp32 store, 1 = bf16 store.
// LDS row-major [rows][8 x 16B chunks], chunk pos XOR-swizzled by (row&7).
// XCD-aware chunked blockIdx swizzle (requires nwg % 8 == 0; launches comply).
template <int BM, int BN, int OUTMODE>
__global__ __launch_bounds__(256, 2) void gemm_bt(
    const bf16* __restrict__ A0, int lda0, const bf16* __restrict__ A1, int lda1,
    const bf16* __restrict__ A2p, int lda2,
    const bf16* __restrict__ B0, int ldb0, const bf16* __restrict__ B1, int ldb1,
    const bf16* __restrict__ B2p, int ldb2,
    void* __restrict__ Cout, int ldc, int K1, int K2, int Ktot) {
  constexpr int BK = 64;
  __shared__ __align__(16) bf16 As[BM * BK];
  __shared__ __align__(16) bf16 Bs[BN * BK];

  const int tid  = threadIdx.x;
  const int lane = tid & 63;
  const int ml   = lane & 15;
  const int q    = lane >> 4;
  const int wave = tid >> 6;

  // XCD swizzle: hw block lin%8 ~ XCD id; give each XCD a contiguous chunk.
  const int gx  = gridDim.x;
  const int nwg = gx * gridDim.y;
  int lin = blockIdx.y * gx + blockIdx.x;
  if ((nwg & 7) == 0) lin = (lin & 7) * (nwg >> 3) + (lin >> 3);
  const int gm0 = (lin / gx) * BM;
  const int gn0 = (lin % gx) * BN;

  constexpr int FM = BM / 32;
  constexpr int FN = BN / 32;
  const int wr  = wave >> 1, wc = wave & 1;
  const int wm0 = wr * (BM / 2);
  const int wn0 = wc * (BN / 2);

  f32x4 acc[FM][FN];
  const f32x4 zero = {0.f, 0.f, 0.f, 0.f};
#pragma unroll
  for (int i = 0; i < FM; ++i)
#pragma unroll
    for (int j = 0; j < FN; ++j) acc[i][j] = zero;

  constexpr int NCA = BM * 8 / 256;  // staging instrs per thread (A)
  constexpr int NCB = BN * 8 / 256;

  const int nkt = Ktot / BK;
  for (int kt = 0; kt < nkt; ++kt) {
    const int k0 = kt * BK;
    const bf16* Ap; int lda, ka;
    const bf16* Bp; int ldb, kb;
    if (k0 < K1) {
      Ap = A0;  lda = lda0; ka = k0;      Bp = B0;  ldb = ldb0; kb = k0;
    } else if (k0 < K2) {
      Ap = A1;  lda = lda1; ka = k0 - K1; Bp = B1;  ldb = ldb1; kb = k0 - K1;
    } else {
      Ap = A2p; lda = lda2; ka = k0 - K2; Bp = B2p; ldb = ldb2; kb = k0 - K2;
    }

    __syncthreads();  // all waves done reading previous tile's LDS

#pragma unroll
    for (int it = 0; it < NCA; ++it) {
      const int Cb = it * 256 + wave * 64;   // wave-uniform chunk base
      const int C  = Cb + lane;
      const int m  = C >> 3;
      const int jg = (C & 7) ^ (m & 7);      // un-swizzle on global side
      async_cp16(Ap + (size_t)(gm0 + m) * lda + ka + jg * 8, &As[Cb * 8]);
    }
#pragma unroll
    for (int it = 0; it < NCB; ++it) {
      const int Cb = it * 256 + wave * 64;
      const int C  = Cb + lane;
      const int n  = C >> 3;
      const int jg = (C & 7) ^ (n & 7);
      async_cp16(Bp + (size_t)(gn0 + n) * ldb + kb + jg * 8, &Bs[Cb * 8]);
    }

    __syncthreads();  // compiler drains vmcnt before s_barrier -> LDS visible

#pragma unroll
    for (int s = 0; s < 2; ++s) {
      bf16x8 af[FM], bfr[FN];
#pragma unroll
      for (int i = 0; i < FM; ++i) {
        const int m = wm0 + i * 16 + ml;
        const int j = (s * 4 + q) ^ (m & 7);
        af[i] = *(const bf16x8*)&As[(m * 8 + j) * 8];
      }
#pragma unroll
      for (int jn = 0; jn < FN; ++jn) {
        const int n = wn0 + jn * 16 + ml;
        const int j = (s * 4 + q) ^ (n & 7);
        bfr[jn] = *(const bf16x8*)&Bs[(n * 8 + j) * 8];
      }
#pragma unroll
      for (int i = 0; i < FM; ++i)
#pragma unroll
        for (int jn = 0; jn < FN; ++jn)
          acc[i][jn] = __builtin_amdgcn_mfma_f32_16x16x32_bf16(af[i], bfr[jn], acc[i][jn], 0, 0, 0);
    }
  }

  // C/D layout: col=lane&15, row=(lane>>4)*4+reg
#pragma unroll
  for (int i = 0; i < FM; ++i) {
#pragma unroll
    for (int jn = 0; jn < FN; ++jn) {
      const int row = gm0 + wm0 + i * 16 + q * 4;
      const int col = gn0 + wn0 + jn * 16 + ml;
#pragma unroll
      for (int r = 0; r < 4; ++r) {
        if constexpr (OUTMODE == 1)
          ((bf16*)Cout)[(size_t)(row + r) * ldc + col] = (bf16)acc[i][jn][r];
        else
          ((float*)Cout)[(size_t)(row + r) * ldc + col] = acc[i][jn][r];
      }
    }
  }
}

// One wave per token: fp32 gate logits (sum of ncomp 128-wide components in a
// gld-wide Gg row) -> exact top-2 softmax; scale the bf16 z values already
// sitting in A2[t][0:256] in-place; fill cols 256..319.
__global__ void router_kernel(const float* __restrict__ Gg, bf16* __restrict__ A2,
                              int gld, int ncomp) {
  const int wave = threadIdx.x >> 6, lane = threadIdx.x & 63;
  const int t = blockIdx.x * 4 + wave;
  const float* g = Gg + (size_t)t * gld;
  float g1 = 0.f, g2 = 0.f;
  for (int cc = 0; cc < ncomp; ++cc) {
    g1 += g[cc * 128 + lane];
    g2 += g[cc * 128 + 64 + lane];
  }
  float s1 = g1 * g1, s2 = g2 * g2;
#pragma unroll
  for (int off = 1; off < 16; off <<= 1) {
    s1 += __shfl_xor(s1, off, 64);
    s2 += __shfl_xor(s2, off, 64);
  }
  float lg[8];
#pragma unroll
  for (int e = 0; e < 4; ++e) {
    lg[e]     = sqrtf(__shfl(s1, e * 16, 64));
    lg[e + 4] = sqrtf(__shfl(s2, e * 16, 64));
  }
  int i1 = 0; float l1 = lg[0];
#pragma unroll
  for (int e = 1; e < 8; ++e) if (lg[e] > l1) { l1 = lg[e]; i1 = e; }
  int i2 = -1; float l2 = -1e30f;
#pragma unroll
  for (int e = 0; e < 8; ++e) if (e != i1 && lg[e] > l2) { l2 = lg[e]; i2 = e; }
  const float w1 = 1.f / (1.f + expf(l2 - l1));  // exact top-2 softmax renorm
  const float w2 = 1.f - w1;

  bf16* a2 = A2 + (size_t)t * A2C;
#pragma unroll
  for (int c0 = 0; c0 < A2C; c0 += 64) {
    const int c = c0 + lane;
    float v;
    if (c < 256) {
      const int we = c >> 5;
      const float wsel = (we == i1) ? w1 : ((we == i2) ? w2 : 0.f);
      v = (float)a2[c] * wsel;   // z (bf16, written by uni_gemm) scaled in place
    } else if (c < 264) {
      const int we = c - 256;
      v = (we == i1) ? w1 : ((we == i2) ? w2 : 0.f);
    } else if (c == 264) {
      v = 1.f;
    } else {
      v = 0.f;
    }
    a2[c] = (bf16)v;
  }
}

extern "C" void kernel_launch(void* const* d_in, const int* in_sizes, int n_in,
                              void* d_out, int out_size, void* d_ws, size_t ws_size,
                              hipStream_t stream) {
  // size-based dispatch; u/svh share 524288: first = u, second = svh (dict order)
  const float *x = nullptr, *W = nullptr, *b = nullptr, *gw = nullptr;
  const float *u = nullptr, *svh = nullptr, *eb = nullptr;
  int seen524 = 0;
  for (int i = 0; i < n_in; ++i) {
    switch (in_sizes[i]) {
      case 16777216: x  = (const float*)d_in[i]; break;
      case 4194304:  W  = (const float*)d_in[i]; break;
      case 2048:     b  = (const float*)d_in[i]; break;
      case 262144:   gw = (const float*)d_in[i]; break;
      case 524288:   if (seen524++ == 0) u = (const float*)d_in[i];
                     else                svh = (const float*)d_in[i];
                     break;
      case 16384:    eb = (const float*)d_in[i]; break;
      default: break;  // top_k (size 1)
    }
  }
  float* out = (float*)d_out;   // fp32 output (confirmed round 6)

  char* ws = (char*)d_ws;
  // Unified path needs 96.7 MB; fall back to the known-good 53.7 MB layout
  // with the fp32 VALU gate if the harness gave us less.
  const bool unified = (ws_size >= WS_U_TOTAL);

  if (unified) {
    bf16*  xbl = (bf16*)(ws + WS_U_XBL);
    float* Gg  = (float*)(ws + WS_U_GG);
    bf16*  A2  = (bf16*)(ws + WS_U_A2);
    bf16*  B2  = (bf16*)(ws + WS_U_B2);
    bf16*  Bp  = (bf16*)(ws + WS_U_BP);
    bf16*  Wb  = (bf16*)(ws + WS_U_WB);

    prep_kernel<<<1024, 256, 0, stream>>>(x, W, svh, u, eb, b, gw,
                                          xbl, Wb, Bp, B2, 1);

    // Uniform small GEMM: 640 identical 128x64-tile blocks, K=2048 each,
    // per-block operand select (see uni_gemm header). 21.5 GF total (half of
    // R4's padded version), direct stores, no atomics, no memsets.
    uni_gemm<<<640, 256, 0, stream>>>(xbl, Bp, Gg, A2);

    router_kernel<<<T_TOK / 4, 256, 0, stream>>>(Gg, A2, 384, 3);

    // out = [xh | A2] @ [Wb | B2]^T (pre + moe + both biases), fp32 store.
    // xh read straight from xbl via lda=4096 (segment 0 only touches k<2048).
    gemm_bt<128, 128, 0><<<dim3(OUT_F / 128, T_TOK / 128), 256, 0, stream>>>(
        xbl, XBL_LD, A2, A2C, A2, A2C, Wb, IN_F, B2, A2C, B2, A2C,
        (void*)out, OUT_F, IN_F, K2_TOT, K2_TOT);
  } else {
    bf16*  xb = (bf16*)(ws + WS_F_XB);
    float* Gg = (float*)(ws + WS_F_GG);
    bf16*  A2 = (bf16*)(ws + WS_F_A2);
    bf16*  B2 = (bf16*)(ws + WS_F_B2);
    bf16*  Wz = (bf16*)(ws + WS_F_WZ);
    bf16*  Wb = (bf16*)(ws + WS_F_WB);

    prep_kernel<<<1024, 256, 0, stream>>>(x, W, svh, u, eb, b, gw,
                                          xb, Wb, Wz, B2, 0);

    hipMemsetAsync(Gg, 0, (size_t)T_TOK * GATE_N * 4, stream);
    vgemm_gate<<<dim3(2, T_TOK / 64, GATE_KS), 256, 0, stream>>>(x, gw, Gg);
    gemm_bt<64, 64, 1><<<dim3(Z_COLS / 64, T_TOK / 64), 256, 0, stream>>>(
        xb, IN_F, xb, IN_F, xb, IN_F, Wz, IN_F, Wz, IN_F, Wz, IN_F,
        (void*)A2, A2C, IN_F, IN_F, IN_F);

    router_kernel<<<T_TOK / 4, 256, 0, stream>>>(Gg, A2, 128, 1);

    gemm_bt<128, 128, 0><<<dim3(OUT_F / 128, T_TOK / 128), 256, 0, stream>>>(
        xb, IN_F, A2, A2C, A2, A2C, Wb, IN_F, B2, A2C, B2, A2C,
        (void*)out, OUT_F, IN_F, K2_TOT, K2_TOT);
  }
}

// Round 6
// 259.296 us; speedup vs baseline: 1.1666x; 1.0307x over previous
//
#include <hip/hip_runtime.h>
#include <cstdint>

typedef __bf16 bf16;
typedef __attribute__((ext_vector_type(8))) __bf16 bf16x8;
typedef __attribute__((ext_vector_type(4))) __bf16 bf16x4;
typedef __attribute__((ext_vector_type(4))) float f32x4;

#define T_TOK 8192
#define IN_F  2048
#define OUT_F 2048
#define GATE_N 128    // E * GK = 8 * 16
#define Z_COLS 256    // svh rows (8 experts x 32)
#define A2C 320       // 256 zw + 8 w + 1 one + 55 zero pad
#define K2_TOT 2368   // 2048 + 320
#define GATE_KS 4     // split-K slices for fp32 gate GEMM (fallback path)
#define UN_N  640     // small-GEMM output cols: 256 z + 3*128 gate comps
#define BP_R  512     // packed B rows: 256 Wz + 128 gh + 128 gl
#define XBL_LD 4096   // xbl row stride: [xh | xl]

// ---- workspace layout, UNIFIED path (bytes) ----
#define WS_U_XBL 0                    // bf16 xbl  8192*4096*2 = 67108864  [xh|xl]
#define WS_U_GG  67108864             // fp32 Gg   8192*384*4  = 12582912  (3 components)
#define WS_U_A2  79691776             // bf16 A2   8192*320*2  =  5242880
#define WS_U_B2  84934656             // bf16 B2   2048*320*2  =  1310720
#define WS_U_BP  86245376             // bf16 Bp   512*2048*2  =  2097152
#define WS_U_WB  88342528             // bf16 Wb   2048*2048*2 =  8388608
#define WS_U_TOTAL 96731136ULL

// ---- workspace layout, FALLBACK path (known-good 53.7 MB) ----
#define WS_F_XB  0
#define WS_F_GG  33554432
#define WS_F_A2  37748736
#define WS_F_B2  42991616
#define WS_F_WZ  44302336
#define WS_F_WB  45350912

// async 16B global->LDS; LDS dest is wave-uniform base, HW scatters lane i at
// base + i*16 (m104/m108). R1-proven incantation.
__device__ __forceinline__ void async_cp16(const bf16* g, bf16* l) {
  __builtin_amdgcn_global_load_lds(
      (const __attribute__((address_space(1))) void*)reinterpret_cast<uintptr_t>(g),
      (__attribute__((address_space(3))) void*)(uint32_t)reinterpret_cast<uintptr_t>(l),
      16, 0, 0);
}

// Convert fp32 inputs to bf16 workspace tensors.
// unified=1: xout = xbl[8192][4096] rows [xh | xl] (lo half = bf16 residual);
//            WzBp = Bp[512][2048] = rows [Wz; gh; gl] (no padding).
// unified=0: xout = xb[8192][2048] (hi only); WzBp = Wz[256][2048].
__global__ void prep_kernel(const float* __restrict__ x, const float* __restrict__ W,
                            const float* __restrict__ svh,
                            const float* __restrict__ u, const float* __restrict__ eb,
                            const float* __restrict__ b, const float* __restrict__ gw,
                            bf16* __restrict__ xout, bf16* __restrict__ Wb,
                            bf16* __restrict__ WzBp, bf16* __restrict__ B2,
                            int unified) {
  const int idx = blockIdx.x * 256 + threadIdx.x;
  const int nt  = gridDim.x * 256;

  const int nx4 = (T_TOK * IN_F) / 4;
  for (int i = idx; i < nx4; i += nt) {
    const float4 v = ((const float4*)x)[i];
    bf16x4 o = {(bf16)v.x, (bf16)v.y, (bf16)v.z, (bf16)v.w};
    if (unified) {
      const int t = i >> 9;            // 512 float4 per 2048-wide row
      const int c = (i & 511) << 2;
      *(bf16x4*)&xout[(size_t)t * XBL_LD + c] = o;
      bf16x4 l = {(bf16)(v.x - (float)o.x), (bf16)(v.y - (float)o.y),
                  (bf16)(v.z - (float)o.z), (bf16)(v.w - (float)o.w)};
      *(bf16x4*)&xout[(size_t)t * XBL_LD + IN_F + c] = l;
    } else {
      *(bf16x4*)&xout[(size_t)i * 4] = o;
    }
  }

  const int nw4 = (OUT_F * IN_F) / 4;
  for (int i = idx; i < nw4; i += nt) {
    const float4 v = ((const float4*)W)[i];
    bf16x4 o = {(bf16)v.x, (bf16)v.y, (bf16)v.z, (bf16)v.w};
    *(bf16x4*)&Wb[(size_t)i * 4] = o;
  }

  if (unified) {
    // Bp[512][2048]: r<256 -> svh_r; 256..383 -> gh_{r-256}; 384..511 -> gl_{r-384}
    const int nbp4 = BP_R * (IN_F / 4);
    for (int i = idx; i < nbp4; i += nt) {
      const int r  = i >> 9;           // 512 float4 per 2048-wide row
      const int jc = (i & 511) << 2;
      bf16x4 o;
      if (r < 256) {
        const float4 v = *(const float4*)(svh + (size_t)r * IN_F + jc);
        o = bf16x4{(bf16)v.x, (bf16)v.y, (bf16)v.z, (bf16)v.w};
      } else if (r < 384) {
        const float4 v = *(const float4*)(gw + (size_t)(r - 256) * IN_F + jc);
        o = bf16x4{(bf16)v.x, (bf16)v.y, (bf16)v.z, (bf16)v.w};
      } else {
        const float4 v = *(const float4*)(gw + (size_t)(r - 384) * IN_F + jc);
        bf16x4 h = {(bf16)v.x, (bf16)v.y, (bf16)v.z, (bf16)v.w};
        o = bf16x4{(bf16)(v.x - (float)h.x), (bf16)(v.y - (float)h.y),
                   (bf16)(v.z - (float)h.z), (bf16)(v.w - (float)h.w)};
      }
      *(bf16x4*)&WzBp[(size_t)i * 4] = o;
    }
  } else {
    const int nz4 = (Z_COLS * IN_F) / 4;   // svh flat [256][2048]
    for (int i = idx; i < nz4; i += nt) {
      const float4 v = ((const float4*)svh)[i];
      bf16x4 o = {(bf16)v.x, (bf16)v.y, (bf16)v.z, (bf16)v.w};
      *(bf16x4*)&WzBp[(size_t)i * 4] = o;
    }
  }

  // B2[o][j]: j<256 -> u[e=j>>5][o][k=j&31]; 256..263 -> eb[j-256][o]; 264 -> b[o]; else 0
  for (int i = idx; i < OUT_F * A2C; i += nt) {
    const int o = i / A2C, j = i - o * A2C;
    float v;
    if (j < 256) {
      const int e = j >> 5, k = j & 31;
      v = u[((size_t)(e * OUT_F + o)) * 32 + k];
    } else if (j < 264) {
      v = eb[(size_t)(j - 256) * OUT_F + o];
    } else if (j == 264) {
      v = b[o];
    } else {
      v = 0.f;
    }
    B2[i] = (bf16)v;
  }
}

// fp32 VALU gate GEMM fallback (only used if ws_size can't fit the unified
// buffers). Split-K x4 (blockIdx.z), atomicAdd epilogue into zeroed Gg.
__global__ __launch_bounds__(256) void vgemm_gate(
    const float* __restrict__ x, const float* __restrict__ gw,
    float* __restrict__ Gg) {
  __shared__ float As[64][37];
  __shared__ float Bs[64][37];
  const int tid = threadIdx.x;
  const int tx = tid & 15, ty = tid >> 4;
  const int gm0 = blockIdx.y * 64, gn0 = blockIdx.x * 64;
  const int kbeg = blockIdx.z * (IN_F / GATE_KS);
  const int kend = kbeg + (IN_F / GATE_KS);

  float acc[4][4] = {};
  for (int k0 = kbeg; k0 < kend; k0 += 32) {
    __syncthreads();
#pragma unroll
    for (int it = 0; it < 2; ++it) {
      const int idx = it * 256 + tid;
      const int r = idx >> 3, c4 = (idx & 7) * 4;
      const float4 av = *(const float4*)(x + (size_t)(gm0 + r) * IN_F + k0 + c4);
      As[r][c4 + 0] = av.x; As[r][c4 + 1] = av.y;
      As[r][c4 + 2] = av.z; As[r][c4 + 3] = av.w;
      const float4 bv = *(const float4*)(gw + (size_t)(gn0 + r) * IN_F + k0 + c4);
      Bs[r][c4 + 0] = bv.x; Bs[r][c4 + 1] = bv.y;
      Bs[r][c4 + 2] = bv.z; Bs[r][c4 + 3] = bv.w;
    }
    __syncthreads();
#pragma unroll 4
    for (int k = 0; k < 32; ++k) {
      float a[4], bb[4];
#pragma unroll
      for (int i = 0; i < 4; ++i) a[i] = As[4 * ty + i][k];
#pragma unroll
      for (int j = 0; j < 4; ++j) bb[j] = Bs[4 * tx + j][k];
#pragma unroll
      for (int i = 0; i < 4; ++i)
#pragma unroll
        for (int j = 0; j < 4; ++j) acc[i][j] += a[i] * bb[j];
    }
  }
#pragma unroll
  for (int i = 0; i < 4; ++i)
#pragma unroll
    for (int j = 0; j < 4; ++j)
      atomicAdd(&Gg[(size_t)(gm0 + 4 * ty + i) * 128 + (gn0 + 4 * tx + j)],
                acc[i][j]);
}

// Uniform small GEMM: C[8192][640] tiles of 128x64, ALL with K=2048.
// Per-block operand select by output column group (no padding, no imbalance):
//   cols   0..255 : A=xh, B=Bp rows n0      (Wz)  -> bf16 A2[.][col]
//   cols 256..511 : A=xh, B=Bp rows n0      (gh/gl) -> fp32 Gg[.][col-256]
//   cols 512..639 : A=xl, B=Bp rows n0-256  (gh)  -> fp32 Gg[.][col-256]
// xh/xl live in xbl[8192][4096] as [xh|xl]; xl = column offset 2048.
// m97 inner structure (async_cp16 staging, XOR swizzle); XCD-chunked swizzle.
__global__ __launch_bounds__(256, 2) void uni_gemm(
    const bf16* __restrict__ xbl, const bf16* __restrict__ Bp,
    float* __restrict__ Gg, bf16* __restrict__ A2) {
  constexpr int BM = 128, BN = 64, BK = 64;
  __shared__ __align__(16) bf16 As[BM * BK];
  __shared__ __align__(16) bf16 Bs[BN * BK];

  const int tid  = threadIdx.x;
  const int lane = tid & 63;
  const int ml   = lane & 15;
  const int q    = lane >> 4;
  const int wave = tid >> 6;

  // grid = 640 blocks (10 col-blocks x 64 row-blocks); 640 % 8 == 0.
  int lin = blockIdx.x;
  lin = (lin & 7) * 80 + (lin >> 3);          // XCD-chunked swizzle
  const int gm0 = (lin / 10) * BM;
  const int n0  = (lin % 10) * BN;            // global output col base
  const int aoff  = (n0 >= 512) ? IN_F : 0;   // xl half for comp-3
  const int brow0 = (n0 >= 512) ? n0 - 256 : n0;

  const int wr = wave >> 1, wc = wave & 1;
  const int wm0 = wr * 64, wn0 = wc * 32;

  f32x4 acc[4][2];
  const f32x4 zero = {0.f, 0.f, 0.f, 0.f};
#pragma unroll
  for (int i = 0; i < 4; ++i)
#pragma unroll
    for (int j = 0; j < 2; ++j) acc[i][j] = zero;

  for (int kt = 0; kt < IN_F / BK; ++kt) {
    const int k0 = kt * BK;

    __syncthreads();  // all waves done reading previous tile's LDS

#pragma unroll
    for (int it = 0; it < 4; ++it) {          // A: 128 rows * 8 chunks / 256
      const int Cb = it * 256 + wave * 64;
      const int C  = Cb + lane;
      const int m  = C >> 3;
      const int jg = (C & 7) ^ (m & 7);
      async_cp16(xbl + (size_t)(gm0 + m) * XBL_LD + aoff + k0 + jg * 8, &As[Cb * 8]);
    }
#pragma unroll
    for (int it = 0; it < 2; ++it) {          // B: 64 rows * 8 chunks / 256
      const int Cb = it * 256 + wave * 64;
      const int C  = Cb + lane;
      const int n  = C >> 3;
      const int jg = (C & 7) ^ (n & 7);
      async_cp16(Bp + (size_t)(brow0 + n) * IN_F + k0 + jg * 8, &Bs[Cb * 8]);
    }

    __syncthreads();  // compiler drains vmcnt before s_barrier -> LDS visible

#pragma unroll
    for (int s = 0; s < 2; ++s) {
      bf16x8 af[4], bfr[2];
#pragma unroll
      for (int i = 0; i < 4; ++i) {
        const int m = wm0 + i * 16 + ml;
        const int j = (s * 4 + q) ^ (m & 7);
        af[i] = *(const bf16x8*)&As[(m * 8 + j) * 8];
      }
#pragma unroll
      for (int jn = 0; jn < 2; ++jn) {
        const int n = wn0 + jn * 16 + ml;
        const int j = (s * 4 + q) ^ (n & 7);
        bfr[jn] = *(const bf16x8*)&Bs[(n * 8 + j) * 8];
      }
#pragma unroll
      for (int i = 0; i < 4; ++i)
#pragma unroll
        for (int jn = 0; jn < 2; ++jn)
          acc[i][jn] = __builtin_amdgcn_mfma_f32_16x16x32_bf16(af[i], bfr[jn], acc[i][jn], 0, 0, 0);
    }
  }

  // C/D layout: col=lane&15, row=(lane>>4)*4+reg. n0 group is block-uniform.
#pragma unroll
  for (int i = 0; i < 4; ++i) {
#pragma unroll
    for (int jn = 0; jn < 2; ++jn) {
      const int row = gm0 + wm0 + i * 16 + q * 4;
      const int col = n0 + wn0 + jn * 16 + ml;
#pragma unroll
      for (int r = 0; r < 4; ++r) {
        if (n0 < 256)
          A2[(size_t)(row + r) * A2C + col] = (bf16)acc[i][jn][r];
        else
          Gg[(size_t)(row + r) * 384 + (col - 256)] = acc[i][jn][r];
      }
    }
  }
}

// Big fused GEMM, 256x256 tile / BK=64 / 512 threads (8 waves 2x4), LDS
// double-buffer + counted vmcnt(8) + raw s_barrier: the next tile's 8
// global_load_lds stay in flight across the barrier (T3/T4 minimum recipe;
// the __syncthreads vmcnt(0) drain was the ~20% stall of the 128^2 version).
// Two K-segments: k<K1 -> (A0 lda0, B0 ldb0); else (A1, B1) at col k-K1.
// Chunk-XOR LDS swizzle identical to gemm_bt (measured 0 bank conflicts).
// fp32 store. Grid dim3(8, 32), bijective XCD-chunked swizzle (nwg=256).
__global__ __launch_bounds__(512, 2) void gemm_big(
    const bf16* __restrict__ A0, int lda0, const bf16* __restrict__ A1, int lda1,
    const bf16* __restrict__ B0, int ldb0, const bf16* __restrict__ B1, int ldb1,
    float* __restrict__ Cout, int ldc, int K1, int Ktot) {
  constexpr int BM = 256, BN = 256, BK = 64;
  __shared__ __align__(16) bf16 As[2][BM * BK / 64 * 64];  // [2][16384]
  __shared__ __align__(16) bf16 Bs[2][BN * BK / 64 * 64];

  const int tid  = threadIdx.x;
  const int lane = tid & 63;
  const int ml   = lane & 15;
  const int q    = lane >> 4;
  const int wave = tid >> 6;

  // XCD-chunked swizzle over 256 blocks (32 per XCD).
  int lin = blockIdx.y * gridDim.x + blockIdx.x;
  lin = (lin & 7) * 32 + (lin >> 3);
  const int gm0 = (lin >> 3) * BM;     // 32 row-blocks
  const int gn0 = (lin & 7) * BN;      // 8 col-blocks

  const int wr = wave >> 2, wc = wave & 3;   // 2 x 4 wave grid
  const int wm0 = wr * 128, wn0 = wc * 64;   // per-wave 128x64 output

  f32x4 acc[8][4];
  const f32x4 zero = {0.f, 0.f, 0.f, 0.f};
#pragma unroll
  for (int i = 0; i < 8; ++i)
#pragma unroll
    for (int j = 0; j < 4; ++j) acc[i][j] = zero;

  const int nkt = Ktot / BK;

  auto stage = [&](int buf, int kt) {
    const int k0 = kt * BK;
    const bf16 *Ap, *Bp; int lda, ldb, ka;
    if (k0 < K1) { Ap = A0; lda = lda0; Bp = B0; ldb = ldb0; ka = k0; }
    else         { Ap = A1; lda = lda1; Bp = B1; ldb = ldb1; ka = k0 - K1; }
#pragma unroll
    for (int it = 0; it < 4; ++it) {          // A: 256 rows * 8 chunks / 512 thr
      const int Cb = it * 512 + wave * 64;    // wave-uniform chunk base
      const int C  = Cb + lane;
      const int m  = C >> 3;
      const int jg = (C & 7) ^ (m & 7);       // un-swizzle on global side
      async_cp16(Ap + (size_t)(gm0 + m) * lda + ka + jg * 8, &As[buf][Cb * 8]);
    }
#pragma unroll
    for (int it = 0; it < 4; ++it) {          // B: 256 rows * 8 chunks / 512 thr
      const int Cb = it * 512 + wave * 64;
      const int C  = Cb + lane;
      const int n  = C >> 3;
      const int jg = (C & 7) ^ (n & 7);
      async_cp16(Bp + (size_t)(gn0 + n) * ldb + ka + jg * 8, &Bs[buf][Cb * 8]);
    }
  };

  auto compute = [&](int buf) {
#pragma unroll
    for (int s = 0; s < 2; ++s) {
      bf16x8 af[8], bfr[4];
#pragma unroll
      for (int i = 0; i < 8; ++i) {
        const int m = wm0 + i * 16 + ml;
        const int j = (s * 4 + q) ^ (m & 7);
        af[i] = *(const bf16x8*)&As[buf][(m * 8 + j) * 8];
      }
#pragma unroll
      for (int jn = 0; jn < 4; ++jn) {
        const int n = wn0 + jn * 16 + ml;
        const int j = (s * 4 + q) ^ (n & 7);
        bfr[jn] = *(const bf16x8*)&Bs[buf][(n * 8 + j) * 8];
      }
      __builtin_amdgcn_s_setprio(1);
#pragma unroll
      for (int i = 0; i < 8; ++i)
#pragma unroll
        for (int jn = 0; jn < 4; ++jn)
          acc[i][jn] = __builtin_amdgcn_mfma_f32_16x16x32_bf16(af[i], bfr[jn], acc[i][jn], 0, 0, 0);
      __builtin_amdgcn_s_setprio(0);
    }
  };

  stage(0, 0);
  int cur = 0;
  for (int kt = 0; kt < nkt - 1; ++kt) {
    stage(cur ^ 1, kt + 1);                       // 8 loads for next tile
    // Wait only the PREVIOUS tile's 8 loads (this tile's 8 are newer) -> the
    // prefetch stays in flight through this tile's MFMAs. Never vmcnt(0) here.
    asm volatile("s_waitcnt vmcnt(8)" ::: "memory");
    __builtin_amdgcn_s_barrier();                 // buf[cur] visible to all
    asm volatile("" ::: "memory");
    compute(cur);
    asm volatile("" ::: "memory");
    __builtin_amdgcn_s_barrier();                 // all waves done reading cur
    asm volatile("" ::: "memory");
    cur ^= 1;
  }
  asm volatile("s_waitcnt vmcnt(0)" ::: "memory");  // drain last tile's loads
  __builtin_amdgcn_s_barrier();
  asm volatile("" ::: "memory");
  compute(cur);

  // C/D layout: col=lane&15, row=(lane>>4)*4+reg
#pragma unroll
  for (int i = 0; i < 8; ++i) {
#pragma unroll
    for (int jn = 0; jn < 4; ++jn) {
      const int row = gm0 + wm0 + i * 16 + q * 4;
      const int col = gn0 + wn0 + jn * 16 + ml;
#pragma unroll
      for (int r = 0; r < 4; ++r)
        Cout[(size_t)(row + r) * ldc + col] = acc[i][jn][r];
    }
  }
}

// bf16 MFMA GEMM (async global_load_lds staging, m97 rung) — fallback path.
// THREE K-segments on absolute k. OUTMODE: 0 = fp32 store, 1 = bf16 store.
template <int BM, int BN, int OUTMODE>
__global__ __launch_bounds__(256, 2) void gemm_bt(
    const bf16* __restrict__ A0, int lda0, const bf16* __restrict__ A1, int lda1,
    const bf16* __restrict__ A2p, int lda2,
    const bf16* __restrict__ B0, int ldb0, const bf16* __restrict__ B1, int ldb1,
    const bf16* __restrict__ B2p, int ldb2,
    void* __restrict__ Cout, int ldc, int K1, int K2, int Ktot) {
  constexpr int BK = 64;
  __shared__ __align__(16) bf16 As[BM * BK];
  __shared__ __align__(16) bf16 Bs[BN * BK];

  const int tid  = threadIdx.x;
  const int lane = tid & 63;
  const int ml   = lane & 15;
  const int q    = lane >> 4;
  const int wave = tid >> 6;

  const int gx  = gridDim.x;
  const int nwg = gx * gridDim.y;
  int lin = blockIdx.y * gx + blockIdx.x;
  if ((nwg & 7) == 0) lin = (lin & 7) * (nwg >> 3) + (lin >> 3);
  const int gm0 = (lin / gx) * BM;
  const int gn0 = (lin % gx) * BN;

  constexpr int FM = BM / 32;
  constexpr int FN = BN / 32;
  const int wr  = wave >> 1, wc = wave & 1;
  const int wm0 = wr * (BM / 2);
  const int wn0 = wc * (BN / 2);

  f32x4 acc[FM][FN];
  const f32x4 zero = {0.f, 0.f, 0.f, 0.f};
#pragma unroll
  for (int i = 0; i < FM; ++i)
#pragma unroll
    for (int j = 0; j < FN; ++j) acc[i][j] = zero;

  constexpr int NCA = BM * 8 / 256;
  constexpr int NCB = BN * 8 / 256;

  const int nkt = Ktot / BK;
  for (int kt = 0; kt < nkt; ++kt) {
    const int k0 = kt * BK;
    const bf16* Ap; int lda, ka;
    const bf16* Bp; int ldb, kb;
    if (k0 < K1) {
      Ap = A0;  lda = lda0; ka = k0;      Bp = B0;  ldb = ldb0; kb = k0;
    } else if (k0 < K2) {
      Ap = A1;  lda = lda1; ka = k0 - K1; Bp = B1;  ldb = ldb1; kb = k0 - K1;
    } else {
      Ap = A2p; lda = lda2; ka = k0 - K2; Bp = B2p; ldb = ldb2; kb = k0 - K2;
    }

    __syncthreads();

#pragma unroll
    for (int it = 0; it < NCA; ++it) {
      const int Cb = it * 256 + wave * 64;
      const int C  = Cb + lane;
      const int m  = C >> 3;
      const int jg = (C & 7) ^ (m & 7);
      async_cp16(Ap + (size_t)(gm0 + m) * lda + ka + jg * 8, &As[Cb * 8]);
    }
#pragma unroll
    for (int it = 0; it < NCB; ++it) {
      const int Cb = it * 256 + wave * 64;
      const int C  = Cb + lane;
      const int n  = C >> 3;
      const int jg = (C & 7) ^ (n & 7);
      async_cp16(Bp + (size_t)(gn0 + n) * ldb + kb + jg * 8, &Bs[Cb * 8]);
    }

    __syncthreads();

#pragma unroll
    for (int s = 0; s < 2; ++s) {
      bf16x8 af[FM], bfr[FN];
#pragma unroll
      for (int i = 0; i < FM; ++i) {
        const int m = wm0 + i * 16 + ml;
        const int j = (s * 4 + q) ^ (m & 7);
        af[i] = *(const bf16x8*)&As[(m * 8 + j) * 8];
      }
#pragma unroll
      for (int jn = 0; jn < FN; ++jn) {
        const int n = wn0 + jn * 16 + ml;
        const int j = (s * 4 + q) ^ (n & 7);
        bfr[jn] = *(const bf16x8*)&Bs[(n * 8 + j) * 8];
      }
#pragma unroll
      for (int i = 0; i < FM; ++i)
#pragma unroll
        for (int jn = 0; jn < FN; ++jn)
          acc[i][jn] = __builtin_amdgcn_mfma_f32_16x16x32_bf16(af[i], bfr[jn], acc[i][jn], 0, 0, 0);
    }
  }

#pragma unroll
  for (int i = 0; i < FM; ++i) {
#pragma unroll
    for (int jn = 0; jn < FN; ++jn) {
      const int row = gm0 + wm0 + i * 16 + q * 4;
      const int col = gn0 + wn0 + jn * 16 + ml;
#pragma unroll
      for (int r = 0; r < 4; ++r) {
        if constexpr (OUTMODE == 1)
          ((bf16*)Cout)[(size_t)(row + r) * ldc + col] = (bf16)acc[i][jn][r];
        else
          ((float*)Cout)[(size_t)(row + r) * ldc + col] = acc[i][jn][r];
      }
    }
  }
}

// One wave per token: fp32 gate logits (sum of ncomp 128-wide components in a
// gld-wide Gg row) -> exact top-2 softmax; scale the bf16 z values already
// sitting in A2[t][0:256] in-place; fill cols 256..319.
__global__ void router_kernel(const float* __restrict__ Gg, bf16* __restrict__ A2,
                              int gld, int ncomp) {
  const int wave = threadIdx.x >> 6, lane = threadIdx.x & 63;
  const int t = blockIdx.x * 4 + wave;
  const float* g = Gg + (size_t)t * gld;
  float g1 = 0.f, g2 = 0.f;
  for (int cc = 0; cc < ncomp; ++cc) {
    g1 += g[cc * 128 + lane];
    g2 += g[cc * 128 + 64 + lane];
  }
  float s1 = g1 * g1, s2 = g2 * g2;
#pragma unroll
  for (int off = 1; off < 16; off <<= 1) {
    s1 += __shfl_xor(s1, off, 64);
    s2 += __shfl_xor(s2, off, 64);
  }
  float lg[8];
#pragma unroll
  for (int e = 0; e < 4; ++e) {
    lg[e]     = sqrtf(__shfl(s1, e * 16, 64));
    lg[e + 4] = sqrtf(__shfl(s2, e * 16, 64));
  }
  int i1 = 0; float l1 = lg[0];
#pragma unroll
  for (int e = 1; e < 8; ++e) if (lg[e] > l1) { l1 = lg[e]; i1 = e; }
  int i2 = -1; float l2 = -1e30f;
#pragma unroll
  for (int e = 0; e < 8; ++e) if (e != i1 && lg[e] > l2) { l2 = lg[e]; i2 = e; }
  const float w1 = 1.f / (1.f + expf(l2 - l1));  // exact top-2 softmax renorm
  const float w2 = 1.f - w1;

  bf16* a2 = A2 + (size_t)t * A2C;
#pragma unroll
  for (int c0 = 0; c0 < A2C; c0 += 64) {
    const int c = c0 + lane;
    float v;
    if (c < 256) {
      const int we = c >> 5;
      const float wsel = (we == i1) ? w1 : ((we == i2) ? w2 : 0.f);
      v = (float)a2[c] * wsel;   // z (bf16, written by uni_gemm) scaled in place
    } else if (c < 264) {
      const int we = c - 256;
      v = (we == i1) ? w1 : ((we == i2) ? w2 : 0.f);
    } else if (c == 264) {
      v = 1.f;
    } else {
      v = 0.f;
    }
    a2[c] = (bf16)v;
  }
}

extern "C" void kernel_launch(void* const* d_in, const int* in_sizes, int n_in,
                              void* d_out, int out_size, void* d_ws, size_t ws_size,
                              hipStream_t stream) {
  // size-based dispatch; u/svh share 524288: first = u, second = svh (dict order)
  const float *x = nullptr, *W = nullptr, *b = nullptr, *gw = nullptr;
  const float *u = nullptr, *svh = nullptr, *eb = nullptr;
  int seen524 = 0;
  for (int i = 0; i < n_in; ++i) {
    switch (in_sizes[i]) {
      case 16777216: x  = (const float*)d_in[i]; break;
      case 4194304:  W  = (const float*)d_in[i]; break;
      case 2048:     b  = (const float*)d_in[i]; break;
      case 262144:   gw = (const float*)d_in[i]; break;
      case 524288:   if (seen524++ == 0) u = (const float*)d_in[i];
                     else                svh = (const float*)d_in[i];
                     break;
      case 16384:    eb = (const float*)d_in[i]; break;
      default: break;  // top_k (size 1)
    }
  }
  float* out = (float*)d_out;   // fp32 output (confirmed round 6)

  char* ws = (char*)d_ws;
  // Unified path needs 96.7 MB; fall back to the known-good 53.7 MB layout
  // with the fp32 VALU gate if the harness gave us less.
  const bool unified = (ws_size >= WS_U_TOTAL);

  if (unified) {
    bf16*  xbl = (bf16*)(ws + WS_U_XBL);
    float* Gg  = (float*)(ws + WS_U_GG);
    bf16*  A2  = (bf16*)(ws + WS_U_A2);
    bf16*  B2  = (bf16*)(ws + WS_U_B2);
    bf16*  Bp  = (bf16*)(ws + WS_U_BP);
    bf16*  Wb  = (bf16*)(ws + WS_U_WB);

    prep_kernel<<<1024, 256, 0, stream>>>(x, W, svh, u, eb, b, gw,
                                          xbl, Wb, Bp, B2, 1);

    // Uniform small GEMM: 640 identical 128x64-tile blocks, K=2048 each,
    // per-block operand select (see uni_gemm header). Direct stores.
    uni_gemm<<<640, 256, 0, stream>>>(xbl, Bp, Gg, A2);

    router_kernel<<<T_TOK / 4, 256, 0, stream>>>(Gg, A2, 384, 3);

    // out = [xh | A2] @ [Wb | B2]^T (pre + moe + both biases), fp32 store.
    // 256^2 tile + dbuf + counted vmcnt (gemm_big); xh from xbl via lda=4096.
    gemm_big<<<dim3(8, 32), 512, 0, stream>>>(
        xbl, XBL_LD, A2, A2C, Wb, IN_F, B2, A2C,
        out, OUT_F, IN_F, K2_TOT);
  } else {
    bf16*  xb = (bf16*)(ws + WS_F_XB);
    float* Gg = (float*)(ws + WS_F_GG);
    bf16*  A2 = (bf16*)(ws + WS_F_A2);
    bf16*  B2 = (bf16*)(ws + WS_F_B2);
    bf16*  Wz = (bf16*)(ws + WS_F_WZ);
    bf16*  Wb = (bf16*)(ws + WS_F_WB);

    prep_kernel<<<1024, 256, 0, stream>>>(x, W, svh, u, eb, b, gw,
                                          xb, Wb, Wz, B2, 0);

    hipMemsetAsync(Gg, 0, (size_t)T_TOK * GATE_N * 4, stream);
    vgemm_gate<<<dim3(2, T_TOK / 64, GATE_KS), 256, 0, stream>>>(x, gw, Gg);
    gemm_bt<64, 64, 1><<<dim3(Z_COLS / 64, T_TOK / 64), 256, 0, stream>>>(
        xb, IN_F, xb, IN_F, xb, IN_F, Wz, IN_F, Wz, IN_F, Wz, IN_F,
        (void*)A2, A2C, IN_F, IN_F, IN_F);

    router_kernel<<<T_TOK / 4, 256, 0, stream>>>(Gg, A2, 128, 1);

    gemm_bt<128, 128, 0><<<dim3(OUT_F / 128, T_TOK / 128), 256, 0, stream>>>(
        xb, IN_F, A2, A2C, A2, A2C, Wb, IN_F, B2, A2C, B2, A2C,
        (void*)out, OUT_F, IN_F, K2_TOT, K2_TOT);
  }
}

// Round 7
// 251.133 us; speedup vs baseline: 1.2045x; 1.0325x over previous
//
#include <hip/hip_runtime.h>
#include <cstdint>

typedef __bf16 bf16;
typedef __attribute__((ext_vector_type(8))) __bf16 bf16x8;
typedef __attribute__((ext_vector_type(4))) __bf16 bf16x4;
typedef __attribute__((ext_vector_type(4))) float f32x4;

#define T_TOK 8192
#define IN_F  2048
#define OUT_F 2048
#define GATE_N 128    // E * GK = 8 * 16
#define Z_COLS 256    // svh rows (8 experts x 32)
#define A2C 320       // 256 zw + 8 w + 1 one + 55 zero pad
#define K2_TOT 2368   // 2048 + 320
#define GATE_KS 4     // split-K slices for fp32 gate GEMM (fallback path)
#define UN_N  640     // small-GEMM output cols: 256 z + 3*128 gate comps
#define BP_R  512     // packed B rows: 256 Wz + 128 gh + 128 gl
#define XBL_LD 4096   // xbl row stride: [xh | xl]

// ---- workspace layout, UNIFIED path (bytes) ----
#define WS_U_XBL 0                    // bf16 xbl  8192*4096*2 = 67108864  [xh|xl]
#define WS_U_GG  67108864             // fp32 Gg   8192*384*4  = 12582912  (3 components)
#define WS_U_A2  79691776             // bf16 A2   8192*320*2  =  5242880
#define WS_U_B2  84934656             // bf16 B2   2048*320*2  =  1310720
#define WS_U_BP  86245376             // bf16 Bp   512*2048*2  =  2097152
#define WS_U_WB  88342528             // bf16 Wb   2048*2048*2 =  8388608
#define WS_U_TOTAL 96731136ULL

// ---- workspace layout, FALLBACK path (known-good 53.7 MB) ----
#define WS_F_XB  0
#define WS_F_GG  33554432
#define WS_F_A2  37748736
#define WS_F_B2  42991616
#define WS_F_WZ  44302336
#define WS_F_WB  45350912

// async 16B global->LDS; LDS dest is wave-uniform base, HW scatters lane i at
// base + i*16 (m104/m108). R1-proven incantation.
__device__ __forceinline__ void async_cp16(const bf16* g, bf16* l) {
  __builtin_amdgcn_global_load_lds(
      (const __attribute__((address_space(1))) void*)reinterpret_cast<uintptr_t>(g),
      (__attribute__((address_space(3))) void*)(uint32_t)reinterpret_cast<uintptr_t>(l),
      16, 0, 0);
}

// Convert fp32 inputs to bf16 workspace tensors.
// unified=1: xout = xbl[8192][4096] rows [xh | xl] (lo half = bf16 residual);
//            WzBp = Bp[512][2048] = rows [Wz; gh; gl] (no padding).
// unified=0: xout = xb[8192][2048] (hi only); WzBp = Wz[256][2048].
__global__ void prep_kernel(const float* __restrict__ x, const float* __restrict__ W,
                            const float* __restrict__ svh,
                            const float* __restrict__ u, const float* __restrict__ eb,
                            const float* __restrict__ b, const float* __restrict__ gw,
                            bf16* __restrict__ xout, bf16* __restrict__ Wb,
                            bf16* __restrict__ WzBp, bf16* __restrict__ B2,
                            int unified) {
  const int idx = blockIdx.x * 256 + threadIdx.x;
  const int nt  = gridDim.x * 256;

  const int nx4 = (T_TOK * IN_F) / 4;
  for (int i = idx; i < nx4; i += nt) {
    const float4 v = ((const float4*)x)[i];
    bf16x4 o = {(bf16)v.x, (bf16)v.y, (bf16)v.z, (bf16)v.w};
    if (unified) {
      const int t = i >> 9;            // 512 float4 per 2048-wide row
      const int c = (i & 511) << 2;
      *(bf16x4*)&xout[(size_t)t * XBL_LD + c] = o;
      bf16x4 l = {(bf16)(v.x - (float)o.x), (bf16)(v.y - (float)o.y),
                  (bf16)(v.z - (float)o.z), (bf16)(v.w - (float)o.w)};
      *(bf16x4*)&xout[(size_t)t * XBL_LD + IN_F + c] = l;
    } else {
      *(bf16x4*)&xout[(size_t)i * 4] = o;
    }
  }

  const int nw4 = (OUT_F * IN_F) / 4;
  for (int i = idx; i < nw4; i += nt) {
    const float4 v = ((const float4*)W)[i];
    bf16x4 o = {(bf16)v.x, (bf16)v.y, (bf16)v.z, (bf16)v.w};
    *(bf16x4*)&Wb[(size_t)i * 4] = o;
  }

  if (unified) {
    // Bp[512][2048]: r<256 -> svh_r; 256..383 -> gh_{r-256}; 384..511 -> gl_{r-384}
    const int nbp4 = BP_R * (IN_F / 4);
    for (int i = idx; i < nbp4; i += nt) {
      const int r  = i >> 9;           // 512 float4 per 2048-wide row
      const int jc = (i & 511) << 2;
      bf16x4 o;
      if (r < 256) {
        const float4 v = *(const float4*)(svh + (size_t)r * IN_F + jc);
        o = bf16x4{(bf16)v.x, (bf16)v.y, (bf16)v.z, (bf16)v.w};
      } else if (r < 384) {
        const float4 v = *(const float4*)(gw + (size_t)(r - 256) * IN_F + jc);
        o = bf16x4{(bf16)v.x, (bf16)v.y, (bf16)v.z, (bf16)v.w};
      } else {
        const float4 v = *(const float4*)(gw + (size_t)(r - 384) * IN_F + jc);
        bf16x4 h = {(bf16)v.x, (bf16)v.y, (bf16)v.z, (bf16)v.w};
        o = bf16x4{(bf16)(v.x - (float)h.x), (bf16)(v.y - (float)h.y),
                   (bf16)(v.z - (float)h.z), (bf16)(v.w - (float)h.w)};
      }
      *(bf16x4*)&WzBp[(size_t)i * 4] = o;
    }
  } else {
    const int nz4 = (Z_COLS * IN_F) / 4;   // svh flat [256][2048]
    for (int i = idx; i < nz4; i += nt) {
      const float4 v = ((const float4*)svh)[i];
      bf16x4 o = {(bf16)v.x, (bf16)v.y, (bf16)v.z, (bf16)v.w};
      *(bf16x4*)&WzBp[(size_t)i * 4] = o;
    }
  }

  // B2[o][j]: j<256 -> u[e=j>>5][o][k=j&31]; 256..263 -> eb[j-256][o]; 264 -> b[o]; else 0
  for (int i = idx; i < OUT_F * A2C; i += nt) {
    const int o = i / A2C, j = i - o * A2C;
    float v;
    if (j < 256) {
      const int e = j >> 5, k = j & 31;
      v = u[((size_t)(e * OUT_F + o)) * 32 + k];
    } else if (j < 264) {
      v = eb[(size_t)(j - 256) * OUT_F + o];
    } else if (j == 264) {
      v = b[o];
    } else {
      v = 0.f;
    }
    B2[i] = (bf16)v;
  }
}

// fp32 VALU gate GEMM fallback (only used if ws_size can't fit the unified
// buffers). Split-K x4 (blockIdx.z), atomicAdd epilogue into zeroed Gg.
__global__ __launch_bounds__(256) void vgemm_gate(
    const float* __restrict__ x, const float* __restrict__ gw,
    float* __restrict__ Gg) {
  __shared__ float As[64][37];
  __shared__ float Bs[64][37];
  const int tid = threadIdx.x;
  const int tx = tid & 15, ty = tid >> 4;
  const int gm0 = blockIdx.y * 64, gn0 = blockIdx.x * 64;
  const int kbeg = blockIdx.z * (IN_F / GATE_KS);
  const int kend = kbeg + (IN_F / GATE_KS);

  float acc[4][4] = {};
  for (int k0 = kbeg; k0 < kend; k0 += 32) {
    __syncthreads();
#pragma unroll
    for (int it = 0; it < 2; ++it) {
      const int idx = it * 256 + tid;
      const int r = idx >> 3, c4 = (idx & 7) * 4;
      const float4 av = *(const float4*)(x + (size_t)(gm0 + r) * IN_F + k0 + c4);
      As[r][c4 + 0] = av.x; As[r][c4 + 1] = av.y;
      As[r][c4 + 2] = av.z; As[r][c4 + 3] = av.w;
      const float4 bv = *(const float4*)(gw + (size_t)(gn0 + r) * IN_F + k0 + c4);
      Bs[r][c4 + 0] = bv.x; Bs[r][c4 + 1] = bv.y;
      Bs[r][c4 + 2] = bv.z; Bs[r][c4 + 3] = bv.w;
    }
    __syncthreads();
#pragma unroll 4
    for (int k = 0; k < 32; ++k) {
      float a[4], bb[4];
#pragma unroll
      for (int i = 0; i < 4; ++i) a[i] = As[4 * ty + i][k];
#pragma unroll
      for (int j = 0; j < 4; ++j) bb[j] = Bs[4 * tx + j][k];
#pragma unroll
      for (int i = 0; i < 4; ++i)
#pragma unroll
        for (int j = 0; j < 4; ++j) acc[i][j] += a[i] * bb[j];
    }
  }
#pragma unroll
  for (int i = 0; i < 4; ++i)
#pragma unroll
    for (int j = 0; j < 4; ++j)
      atomicAdd(&Gg[(size_t)(gm0 + 4 * ty + i) * 128 + (gn0 + 4 * tx + j)],
                acc[i][j]);
}

// Uniform small GEMM: C[8192][640] tiles of 128x64, ALL with K=2048.
// Per-block operand select by output column group (no padding, no imbalance):
//   cols   0..255 : A=xh, B=Bp rows n0      (Wz)  -> bf16 A2[.][col]
//   cols 256..511 : A=xh, B=Bp rows n0      (gh/gl) -> fp32 Gg[.][col-256]
//   cols 512..639 : A=xl, B=Bp rows n0-256  (gh)  -> fp32 Gg[.][col-256]
// xh/xl live in xbl[8192][4096] as [xh|xl]; xl = column offset 2048.
// m97 inner structure (async_cp16 staging, XOR swizzle); XCD-chunked swizzle.
__global__ __launch_bounds__(256, 2) void uni_gemm(
    const bf16* __restrict__ xbl, const bf16* __restrict__ Bp,
    float* __restrict__ Gg, bf16* __restrict__ A2) {
  constexpr int BM = 128, BN = 64, BK = 64;
  __shared__ __align__(16) bf16 As[BM * BK];
  __shared__ __align__(16) bf16 Bs[BN * BK];

  const int tid  = threadIdx.x;
  const int lane = tid & 63;
  const int ml   = lane & 15;
  const int q    = lane >> 4;
  const int wave = tid >> 6;

  // grid = 640 blocks (10 col-blocks x 64 row-blocks); 640 % 8 == 0.
  int lin = blockIdx.x;
  lin = (lin & 7) * 80 + (lin >> 3);          // XCD-chunked swizzle
  const int gm0 = (lin / 10) * BM;
  const int n0  = (lin % 10) * BN;            // global output col base
  const int aoff  = (n0 >= 512) ? IN_F : 0;   // xl half for comp-3
  const int brow0 = (n0 >= 512) ? n0 - 256 : n0;

  const int wr = wave >> 1, wc = wave & 1;
  const int wm0 = wr * 64, wn0 = wc * 32;

  f32x4 acc[4][2];
  const f32x4 zero = {0.f, 0.f, 0.f, 0.f};
#pragma unroll
  for (int i = 0; i < 4; ++i)
#pragma unroll
    for (int j = 0; j < 2; ++j) acc[i][j] = zero;

  for (int kt = 0; kt < IN_F / BK; ++kt) {
    const int k0 = kt * BK;

    __syncthreads();  // all waves done reading previous tile's LDS

#pragma unroll
    for (int it = 0; it < 4; ++it) {          // A: 128 rows * 8 chunks / 256
      const int Cb = it * 256 + wave * 64;
      const int C  = Cb + lane;
      const int m  = C >> 3;
      const int jg = (C & 7) ^ (m & 7);
      async_cp16(xbl + (size_t)(gm0 + m) * XBL_LD + aoff + k0 + jg * 8, &As[Cb * 8]);
    }
#pragma unroll
    for (int it = 0; it < 2; ++it) {          // B: 64 rows * 8 chunks / 256
      const int Cb = it * 256 + wave * 64;
      const int C  = Cb + lane;
      const int n  = C >> 3;
      const int jg = (C & 7) ^ (n & 7);
      async_cp16(Bp + (size_t)(brow0 + n) * IN_F + k0 + jg * 8, &Bs[Cb * 8]);
    }

    __syncthreads();  // compiler drains vmcnt before s_barrier -> LDS visible

#pragma unroll
    for (int s = 0; s < 2; ++s) {
      bf16x8 af[4], bfr[2];
#pragma unroll
      for (int i = 0; i < 4; ++i) {
        const int m = wm0 + i * 16 + ml;
        const int j = (s * 4 + q) ^ (m & 7);
        af[i] = *(const bf16x8*)&As[(m * 8 + j) * 8];
      }
#pragma unroll
      for (int jn = 0; jn < 2; ++jn) {
        const int n = wn0 + jn * 16 + ml;
        const int j = (s * 4 + q) ^ (n & 7);
        bfr[jn] = *(const bf16x8*)&Bs[(n * 8 + j) * 8];
      }
#pragma unroll
      for (int i = 0; i < 4; ++i)
#pragma unroll
        for (int jn = 0; jn < 2; ++jn)
          acc[i][jn] = __builtin_amdgcn_mfma_f32_16x16x32_bf16(af[i], bfr[jn], acc[i][jn], 0, 0, 0);
    }
  }

  // C/D layout: col=lane&15, row=(lane>>4)*4+reg. n0 group is block-uniform.
#pragma unroll
  for (int i = 0; i < 4; ++i) {
#pragma unroll
    for (int jn = 0; jn < 2; ++jn) {
      const int row = gm0 + wm0 + i * 16 + q * 4;
      const int col = n0 + wn0 + jn * 16 + ml;
#pragma unroll
      for (int r = 0; r < 4; ++r) {
        if (n0 < 256)
          A2[(size_t)(row + r) * A2C + col] = (bf16)acc[i][jn][r];
        else
          Gg[(size_t)(row + r) * 384 + (col - 256)] = acc[i][jn][r];
      }
    }
  }
}

// Big fused GEMM, 256x256 tile / BK=64 / 512 threads (8 waves 2x4).
// T3/T4 fine-phase schedule: per K-tile, stage next tile's 8 loads + counted
// vmcnt(8) (prev tile's loads landed; never 0 in main loop), then FOUR
// phases (s, mh): {ds_read 8|4 b128 -> barrier -> setprio(1) -> 16 MFMA ->
// setprio(0)}. The phase barrier absorbs ds_read latency; phase p+1's reads
// overlap phase p's MFMA cluster (different pipes, no fence between them).
// Buffer safety: all reads of a buffer precede that tile's last phase
// barrier; the next stage() (overwriting the other buffer) runs only after
// every wave passed it. Chunk-XOR LDS swizzle identical to gemm_bt
// (measured 0 bank conflicts). fp32 store. Grid dim3(8, 32), bijective
// XCD-chunked swizzle (nwg=256).
__global__ __launch_bounds__(512, 2) void gemm_big(
    const bf16* __restrict__ A0, int lda0, const bf16* __restrict__ A1, int lda1,
    const bf16* __restrict__ B0, int ldb0, const bf16* __restrict__ B1, int ldb1,
    float* __restrict__ Cout, int ldc, int K1, int Ktot) {
  constexpr int BM = 256, BN = 256, BK = 64;
  __shared__ __align__(16) bf16 As[2][BM * BK];  // 2 x 32 KB
  __shared__ __align__(16) bf16 Bs[2][BN * BK];  // 2 x 32 KB

  const int tid  = threadIdx.x;
  const int lane = tid & 63;
  const int ml   = lane & 15;
  const int q    = lane >> 4;
  const int wave = tid >> 6;

  // XCD-chunked swizzle over 256 blocks (32 per XCD).
  int lin = blockIdx.y * gridDim.x + blockIdx.x;
  lin = (lin & 7) * 32 + (lin >> 3);
  const int gm0 = (lin >> 3) * BM;     // 32 row-blocks
  const int gn0 = (lin & 7) * BN;      // 8 col-blocks

  const int wr = wave >> 2, wc = wave & 3;   // 2 x 4 wave grid
  const int wm0 = wr * 128, wn0 = wc * 64;   // per-wave 128x64 output

  f32x4 acc[8][4];
  const f32x4 zero = {0.f, 0.f, 0.f, 0.f};
#pragma unroll
  for (int i = 0; i < 8; ++i)
#pragma unroll
    for (int j = 0; j < 4; ++j) acc[i][j] = zero;

  const int nkt = Ktot / BK;

  auto stage = [&](int buf, int kt) {
    const int k0 = kt * BK;
    const bf16 *Ap, *Bp; int lda, ldb, ka;
    if (k0 < K1) { Ap = A0; lda = lda0; Bp = B0; ldb = ldb0; ka = k0; }
    else         { Ap = A1; lda = lda1; Bp = B1; ldb = ldb1; ka = k0 - K1; }
#pragma unroll
    for (int it = 0; it < 4; ++it) {          // A: 256 rows * 8 chunks / 512 thr
      const int Cb = it * 512 + wave * 64;    // wave-uniform chunk base
      const int C  = Cb + lane;
      const int m  = C >> 3;
      const int jg = (C & 7) ^ (m & 7);       // un-swizzle on global side
      async_cp16(Ap + (size_t)(gm0 + m) * lda + ka + jg * 8, &As[buf][Cb * 8]);
    }
#pragma unroll
    for (int it = 0; it < 4; ++it) {          // B: 256 rows * 8 chunks / 512 thr
      const int Cb = it * 512 + wave * 64;
      const int C  = Cb + lane;
      const int n  = C >> 3;
      const int jg = (C & 7) ^ (n & 7);
      async_cp16(Bp + (size_t)(gn0 + n) * ldb + ka + jg * 8, &Bs[buf][Cb * 8]);
    }
  };

  stage(0, 0);
  int cur = 0;
  for (int kt = 0; kt < nkt; ++kt) {
    if (kt + 1 < nkt) {
      stage(cur ^ 1, kt + 1);                 // 8 loads for next tile
      // Wait only the PREVIOUS tile's 8 loads (this tile's 8 are newer):
      // the prefetch stays in flight through this tile's phases.
      asm volatile("s_waitcnt vmcnt(8)" ::: "memory");
    } else {
      asm volatile("s_waitcnt vmcnt(0)" ::: "memory");  // drain final tile
    }
    __builtin_amdgcn_s_barrier();             // buf[cur] visible to all waves
    asm volatile("" ::: "memory");

    const bf16* Asc = As[cur];
    const bf16* Bsc = Bs[cur];
    bf16x8 af[4], bfr[4];

#pragma unroll
    for (int s = 0; s < 2; ++s) {
#pragma unroll
      for (int mh = 0; mh < 2; ++mh) {
        // ---- phase (s, mh): reads, barrier, 16-MFMA cluster ----
        if (mh == 0) {                         // bfr for this k-slot: 4 reads
#pragma unroll
          for (int jn = 0; jn < 4; ++jn) {
            const int n = wn0 + jn * 16 + ml;
            const int j = (s * 4 + q) ^ (n & 7);
            bfr[jn] = *(const bf16x8*)&Bsc[(n * 8 + j) * 8];
          }
        }
#pragma unroll
        for (int i4 = 0; i4 < 4; ++i4) {       // af half: 4 reads
          const int m = wm0 + (mh * 4 + i4) * 16 + ml;
          const int j = (s * 4 + q) ^ (m & 7);
          af[i4] = *(const bf16x8*)&Asc[(m * 8 + j) * 8];
        }
        asm volatile("" ::: "memory");
        __builtin_amdgcn_s_barrier();          // absorbs ds_read latency
        asm volatile("" ::: "memory");
        __builtin_amdgcn_s_setprio(1);
#pragma unroll
        for (int i4 = 0; i4 < 4; ++i4)
#pragma unroll
          for (int jn = 0; jn < 4; ++jn)
            acc[mh * 4 + i4][jn] = __builtin_amdgcn_mfma_f32_16x16x32_bf16(
                af[i4], bfr[jn], acc[mh * 4 + i4][jn], 0, 0, 0);
        __builtin_amdgcn_s_setprio(0);
      }
    }
    cur ^= 1;
  }

  // C/D layout: col=lane&15, row=(lane>>4)*4+reg
#pragma unroll
  for (int i = 0; i < 8; ++i) {
#pragma unroll
    for (int jn = 0; jn < 4; ++jn) {
      const int row = gm0 + wm0 + i * 16 + q * 4;
      const int col = gn0 + wn0 + jn * 16 + ml;
#pragma unroll
      for (int r = 0; r < 4; ++r)
        Cout[(size_t)(row + r) * ldc + col] = acc[i][jn][r];
    }
  }
}

// bf16 MFMA GEMM (async global_load_lds staging, m97 rung) — fallback path.
// THREE K-segments on absolute k. OUTMODE: 0 = fp32 store, 1 = bf16 store.
template <int BM, int BN, int OUTMODE>
__global__ __launch_bounds__(256, 2) void gemm_bt(
    const bf16* __restrict__ A0, int lda0, const bf16* __restrict__ A1, int lda1,
    const bf16* __restrict__ A2p, int lda2,
    const bf16* __restrict__ B0, int ldb0, const bf16* __restrict__ B1, int ldb1,
    const bf16* __restrict__ B2p, int ldb2,
    void* __restrict__ Cout, int ldc, int K1, int K2, int Ktot) {
  constexpr int BK = 64;
  __shared__ __align__(16) bf16 As[BM * BK];
  __shared__ __align__(16) bf16 Bs[BN * BK];

  const int tid  = threadIdx.x;
  const int lane = tid & 63;
  const int ml   = lane & 15;
  const int q    = lane >> 4;
  const int wave = tid >> 6;

  const int gx  = gridDim.x;
  const int nwg = gx * gridDim.y;
  int lin = blockIdx.y * gx + blockIdx.x;
  if ((nwg & 7) == 0) lin = (lin & 7) * (nwg >> 3) + (lin >> 3);
  const int gm0 = (lin / gx) * BM;
  const int gn0 = (lin % gx) * BN;

  constexpr int FM = BM / 32;
  constexpr int FN = BN / 32;
  const int wr  = wave >> 1, wc = wave & 1;
  const int wm0 = wr * (BM / 2);
  const int wn0 = wc * (BN / 2);

  f32x4 acc[FM][FN];
  const f32x4 zero = {0.f, 0.f, 0.f, 0.f};
#pragma unroll
  for (int i = 0; i < FM; ++i)
#pragma unroll
    for (int j = 0; j < FN; ++j) acc[i][j] = zero;

  constexpr int NCA = BM * 8 / 256;
  constexpr int NCB = BN * 8 / 256;

  const int nkt = Ktot / BK;
  for (int kt = 0; kt < nkt; ++kt) {
    const int k0 = kt * BK;
    const bf16* Ap; int lda, ka;
    const bf16* Bp; int ldb, kb;
    if (k0 < K1) {
      Ap = A0;  lda = lda0; ka = k0;      Bp = B0;  ldb = ldb0; kb = k0;
    } else if (k0 < K2) {
      Ap = A1;  lda = lda1; ka = k0 - K1; Bp = B1;  ldb = ldb1; kb = k0 - K1;
    } else {
      Ap = A2p; lda = lda2; ka = k0 - K2; Bp = B2p; ldb = ldb2; kb = k0 - K2;
    }

    __syncthreads();

#pragma unroll
    for (int it = 0; it < NCA; ++it) {
      const int Cb = it * 256 + wave * 64;
      const int C  = Cb + lane;
      const int m  = C >> 3;
      const int jg = (C & 7) ^ (m & 7);
      async_cp16(Ap + (size_t)(gm0 + m) * lda + ka + jg * 8, &As[Cb * 8]);
    }
#pragma unroll
    for (int it = 0; it < NCB; ++it) {
      const int Cb = it * 256 + wave * 64;
      const int C  = Cb + lane;
      const int n  = C >> 3;
      const int jg = (C & 7) ^ (n & 7);
      async_cp16(Bp + (size_t)(gn0 + n) * ldb + kb + jg * 8, &Bs[Cb * 8]);
    }

    __syncthreads();

#pragma unroll
    for (int s = 0; s < 2; ++s) {
      bf16x8 af[FM], bfr[FN];
#pragma unroll
      for (int i = 0; i < FM; ++i) {
        const int m = wm0 + i * 16 + ml;
        const int j = (s * 4 + q) ^ (m & 7);
        af[i] = *(const bf16x8*)&As[(m * 8 + j) * 8];
      }
#pragma unroll
      for (int jn = 0; jn < FN; ++jn) {
        const int n = wn0 + jn * 16 + ml;
        const int j = (s * 4 + q) ^ (n & 7);
        bfr[jn] = *(const bf16x8*)&Bs[(n * 8 + j) * 8];
      }
#pragma unroll
      for (int i = 0; i < FM; ++i)
#pragma unroll
        for (int jn = 0; jn < FN; ++jn)
          acc[i][jn] = __builtin_amdgcn_mfma_f32_16x16x32_bf16(af[i], bfr[jn], acc[i][jn], 0, 0, 0);
    }
  }

#pragma unroll
  for (int i = 0; i < FM; ++i) {
#pragma unroll
    for (int jn = 0; jn < FN; ++jn) {
      const int row = gm0 + wm0 + i * 16 + q * 4;
      const int col = gn0 + wn0 + jn * 16 + ml;
#pragma unroll
      for (int r = 0; r < 4; ++r) {
        if constexpr (OUTMODE == 1)
          ((bf16*)Cout)[(size_t)(row + r) * ldc + col] = (bf16)acc[i][jn][r];
        else
          ((float*)Cout)[(size_t)(row + r) * ldc + col] = acc[i][jn][r];
      }
    }
  }
}

// One wave per token: fp32 gate logits (sum of ncomp 128-wide components in a
// gld-wide Gg row) -> exact top-2 softmax; scale the bf16 z values already
// sitting in A2[t][0:256] in-place; fill cols 256..319.
__global__ void router_kernel(const float* __restrict__ Gg, bf16* __restrict__ A2,
                              int gld, int ncomp) {
  const int wave = threadIdx.x >> 6, lane = threadIdx.x & 63;
  const int t = blockIdx.x * 4 + wave;
  const float* g = Gg + (size_t)t * gld;
  float g1 = 0.f, g2 = 0.f;
  for (int cc = 0; cc < ncomp; ++cc) {
    g1 += g[cc * 128 + lane];
    g2 += g[cc * 128 + 64 + lane];
  }
  float s1 = g1 * g1, s2 = g2 * g2;
#pragma unroll
  for (int off = 1; off < 16; off <<= 1) {
    s1 += __shfl_xor(s1, off, 64);
    s2 += __shfl_xor(s2, off, 64);
  }
  float lg[8];
#pragma unroll
  for (int e = 0; e < 4; ++e) {
    lg[e]     = sqrtf(__shfl(s1, e * 16, 64));
    lg[e + 4] = sqrtf(__shfl(s2, e * 16, 64));
  }
  int i1 = 0; float l1 = lg[0];
#pragma unroll
  for (int e = 1; e < 8; ++e) if (lg[e] > l1) { l1 = lg[e]; i1 = e; }
  int i2 = -1; float l2 = -1e30f;
#pragma unroll
  for (int e = 0; e < 8; ++e) if (e != i1 && lg[e] > l2) { l2 = lg[e]; i2 = e; }
  const float w1 = 1.f / (1.f + expf(l2 - l1));  // exact top-2 softmax renorm
  const float w2 = 1.f - w1;

  bf16* a2 = A2 + (size_t)t * A2C;
#pragma unroll
  for (int c0 = 0; c0 < A2C; c0 += 64) {
    const int c = c0 + lane;
    float v;
    if (c < 256) {
      const int we = c >> 5;
      const float wsel = (we == i1) ? w1 : ((we == i2) ? w2 : 0.f);
      v = (float)a2[c] * wsel;   // z (bf16, written by uni_gemm) scaled in place
    } else if (c < 264) {
      const int we = c - 256;
      v = (we == i1) ? w1 : ((we == i2) ? w2 : 0.f);
    } else if (c == 264) {
      v = 1.f;
    } else {
      v = 0.f;
    }
    a2[c] = (bf16)v;
  }
}

extern "C" void kernel_launch(void* const* d_in, const int* in_sizes, int n_in,
                              void* d_out, int out_size, void* d_ws, size_t ws_size,
                              hipStream_t stream) {
  // size-based dispatch; u/svh share 524288: first = u, second = svh (dict order)
  const float *x = nullptr, *W = nullptr, *b = nullptr, *gw = nullptr;
  const float *u = nullptr, *svh = nullptr, *eb = nullptr;
  int seen524 = 0;
  for (int i = 0; i < n_in; ++i) {
    switch (in_sizes[i]) {
      case 16777216: x  = (const float*)d_in[i]; break;
      case 4194304:  W  = (const float*)d_in[i]; break;
      case 2048:     b  = (const float*)d_in[i]; break;
      case 262144:   gw = (const float*)d_in[i]; break;
      case 524288:   if (seen524++ == 0) u = (const float*)d_in[i];
                     else                svh = (const float*)d_in[i];
                     break;
      case 16384:    eb = (const float*)d_in[i]; break;
      default: break;  // top_k (size 1)
    }
  }
  float* out = (float*)d_out;   // fp32 output (confirmed round 6)

  char* ws = (char*)d_ws;
  // Unified path needs 96.7 MB; fall back to the known-good 53.7 MB layout
  // with the fp32 VALU gate if the harness gave us less.
  const bool unified = (ws_size >= WS_U_TOTAL);

  if (unified) {
    bf16*  xbl = (bf16*)(ws + WS_U_XBL);
    float* Gg  = (float*)(ws + WS_U_GG);
    bf16*  A2  = (bf16*)(ws + WS_U_A2);
    bf16*  B2  = (bf16*)(ws + WS_U_B2);
    bf16*  Bp  = (bf16*)(ws + WS_U_BP);
    bf16*  Wb  = (bf16*)(ws + WS_U_WB);

    prep_kernel<<<1024, 256, 0, stream>>>(x, W, svh, u, eb, b, gw,
                                          xbl, Wb, Bp, B2, 1);

    // Uniform small GEMM: 640 identical 128x64-tile blocks, K=2048 each,
    // per-block operand select (see uni_gemm header). Direct stores.
    uni_gemm<<<640, 256, 0, stream>>>(xbl, Bp, Gg, A2);

    router_kernel<<<T_TOK / 4, 256, 0, stream>>>(Gg, A2, 384, 3);

    // out = [xh | A2] @ [Wb | B2]^T (pre + moe + both biases), fp32 store.
    // 256^2 tile, 4-phase fine interleave + counted vmcnt (gemm_big).
    gemm_big<<<dim3(8, 32), 512, 0, stream>>>(
        xbl, XBL_LD, A2, A2C, Wb, IN_F, B2, A2C,
        out, OUT_F, IN_F, K2_TOT);
  } else {
    bf16*  xb = (bf16*)(ws + WS_F_XB);
    float* Gg = (float*)(ws + WS_F_GG);
    bf16*  A2 = (bf16*)(ws + WS_F_A2);
    bf16*  B2 = (bf16*)(ws + WS_F_B2);
    bf16*  Wz = (bf16*)(ws + WS_F_WZ);
    bf16*  Wb = (bf16*)(ws + WS_F_WB);

    prep_kernel<<<1024, 256, 0, stream>>>(x, W, svh, u, eb, b, gw,
                                          xb, Wb, Wz, B2, 0);

    hipMemsetAsync(Gg, 0, (size_t)T_TOK * GATE_N * 4, stream);
    vgemm_gate<<<dim3(2, T_TOK / 64, GATE_KS), 256, 0, stream>>>(x, gw, Gg);
    gemm_bt<64, 64, 1><<<dim3(Z_COLS / 64, T_TOK / 64), 256, 0, stream>>>(
        xb, IN_F, xb, IN_F, xb, IN_F, Wz, IN_F, Wz, IN_F, Wz, IN_F,
        (void*)A2, A2C, IN_F, IN_F, IN_F);

    router_kernel<<<T_TOK / 4, 256, 0, stream>>>(Gg, A2, 128, 1);

    gemm_bt<128, 128, 0><<<dim3(OUT_F / 128, T_TOK / 128), 256, 0, stream>>>(
        xb, IN_F, A2, A2C, A2, A2C, Wb, IN_F, B2, A2C, B2, A2C,
        (void*)out, OUT_F, IN_F, K2_TOT, K2_TOT);
  }
}